// Round 2
// baseline (3713.799 us; speedup 1.0000x reference)
//
#include <hip/hip_runtime.h>

typedef __attribute__((ext_vector_type(8))) short short8;
typedef __attribute__((ext_vector_type(4))) float f32x4;
typedef __attribute__((ext_vector_type(2))) float f32x2;
typedef __attribute__((ext_vector_type(4))) unsigned short us4;

__device__ __forceinline__ unsigned short bf16_of(float f) {
    unsigned u = __builtin_bit_cast(unsigned, f);
    u += 0x7fffu + ((u >> 16) & 1u);   // RNE
    return (unsigned short)(u >> 16);
}
__device__ __forceinline__ float fexp2(float x) { return __builtin_amdgcn_exp2f(x); }
__device__ __forceinline__ float frcp(float x) { return __builtin_amdgcn_rcpf(x); }
__device__ __forceinline__ float sigm(float x) { return frcp(1.f + fexp2(-1.44269504f * x)); }
__device__ __forceinline__ float tanh_f(float x) {
    float e = fexp2(2.88539008f * x);   // e^(2x)
    return 1.f - 2.f * frcp(e + 1.f);
}
__device__ __forceinline__ f32x4 mfma16(short8 a, short8 b, f32x4 c) {
    return __builtin_amdgcn_mfma_f32_16x16x32_bf16(a, b, c, 0, 0, 0);
}

// ---------------------------------------------------------------------------
// Generic fp32 GEMM: C[M,N] = A[M,K] @ B (+bias) (optional relu)
// BT=0: B is [K,N] row-major.  BT=1: B is [N,K] row-major (i.e. use B^T).
// M mult of 64, N mult of 64, K mult of 32.
__global__ __launch_bounds__(256) void gemm_f32(
    const float* __restrict__ A, const float* __restrict__ B,
    const float* __restrict__ bias, float* __restrict__ C,
    int M, int N, int K, int BT, int RELU)
{
    __shared__ float As[64][33];
    __shared__ float Bs[32][68];
    const int tid = threadIdx.x;
    const int tx = tid & 15, ty = tid >> 4;
    const int m0 = blockIdx.y * 64, n0 = blockIdx.x * 64;
    float acc[4][4];
#pragma unroll
    for (int i = 0; i < 4; ++i)
#pragma unroll
        for (int j = 0; j < 4; ++j) acc[i][j] = 0.f;

    for (int k0 = 0; k0 < K; k0 += 32) {
        __syncthreads();
        {   // stage A 64x32
            const int r = tid >> 2, kk = (tid & 3) * 8;
            const float* src = A + (size_t)(m0 + r) * K + k0 + kk;
            f32x4 v0 = *(const f32x4*)src;
            f32x4 v1 = *(const f32x4*)(src + 4);
#pragma unroll
            for (int e = 0; e < 4; ++e) { As[r][kk + e] = v0[e]; As[r][kk + 4 + e] = v1[e]; }
        }
        if (!BT) {  // stage B 32x64
            const int kk = tid >> 3, nn = (tid & 7) * 8;
            const float* src = B + (size_t)(k0 + kk) * N + n0 + nn;
            f32x4 v0 = *(const f32x4*)src;
            f32x4 v1 = *(const f32x4*)(src + 4);
#pragma unroll
            for (int e = 0; e < 4; ++e) { Bs[kk][nn + e] = v0[e]; Bs[kk][nn + 4 + e] = v1[e]; }
        } else {    // B given [N,K]: transpose-stage
            const int n = tid >> 2, kk = (tid & 3) * 8;
            const float* src = B + (size_t)(n0 + n) * K + k0 + kk;
            f32x4 v0 = *(const f32x4*)src;
            f32x4 v1 = *(const f32x4*)(src + 4);
#pragma unroll
            for (int e = 0; e < 4; ++e) { Bs[kk + e][n] = v0[e]; Bs[kk + 4 + e][n] = v1[e]; }
        }
        __syncthreads();
#pragma unroll 8
        for (int k = 0; k < 32; ++k) {
            float a0 = As[ty * 4 + 0][k], a1 = As[ty * 4 + 1][k];
            float a2 = As[ty * 4 + 2][k], a3 = As[ty * 4 + 3][k];
            f32x4 bv = *(const f32x4*)&Bs[k][tx * 4];
#pragma unroll
            for (int j = 0; j < 4; ++j) {
                acc[0][j] += a0 * bv[j]; acc[1][j] += a1 * bv[j];
                acc[2][j] += a2 * bv[j]; acc[3][j] += a3 * bv[j];
            }
        }
    }
    f32x4 bv = {};
    if (bias != nullptr) bv = *(const f32x4*)&bias[n0 + tx * 4];
#pragma unroll
    for (int i = 0; i < 4; ++i) {
        f32x4 res = {};
#pragma unroll
        for (int j = 0; j < 4; ++j) {
            float v = acc[i][j] + bv[j];
            if (RELU) v = fmaxf(v, 0.f);
            res[j] = v;
        }
        *(f32x4*)&C[(size_t)(m0 + ty * 4 + i) * N + n0 + tx * 4] = res;
    }
}

// ---------------------------------------------------------------------------
// si[b,n] = h[b,n,:]·aW[128:256],  sj[b,n] = h[b,n,:]·aW[0:128]
__global__ __launch_bounds__(256) void sisj_kernel(
    const float* __restrict__ h, const float* __restrict__ aW,
    float* __restrict__ si, float* __restrict__ sj)
{
    const int tid = threadIdx.x, lane = tid & 63, w = tid >> 6;
    const int row = blockIdx.x * 4 + w;  // 0..8191
    f32x2 hv = *(const f32x2*)(h + (size_t)row * 128 + lane * 2);
    f32x2 w1 = *(const f32x2*)&aW[lane * 2];
    f32x2 w2 = *(const f32x2*)&aW[128 + lane * 2];
    float sjp = hv[0] * w1[0] + hv[1] * w1[1];
    float sip = hv[0] * w2[0] + hv[1] * w2[1];
#pragma unroll
    for (int o = 32; o > 0; o >>= 1) {
        sjp += __shfl_xor(sjp, o);
        sip += __shfl_xor(sip, o);
    }
    if (lane == 0) { si[row] = sip; sj[row] = sjp; }
}

// ---------------------------------------------------------------------------
// hT[b][d][j] = bf16(h[b][j][d])   (for MFMA B staging)
__global__ __launch_bounds__(256) void transpose_bf16_k(
    const float* __restrict__ h, unsigned short* __restrict__ hT)
{
    __shared__ float t[64][65];
    const int b = blockIdx.z, jt = blockIdx.x, dt = blockIdx.y;
    const int tid = threadIdx.x;
    const int r = tid >> 4, c4 = (tid & 15) * 4;
#pragma unroll
    for (int rr = 0; rr < 4; ++rr) {
        const int j = rr * 16 + r;
        f32x4 v = *(const f32x4*)(h + ((size_t)b * 1024 + jt * 64 + j) * 128 + dt * 64 + c4);
#pragma unroll
        for (int e = 0; e < 4; ++e) t[j][c4 + e] = v[e];
    }
    __syncthreads();
#pragma unroll
    for (int rr = 0; rr < 4; ++rr) {
        const int d = rr * 16 + r;
        us4 o;
#pragma unroll
        for (int e = 0; e < 4; ++e) o[e] = bf16_of(t[c4 + e][d]);
        *(us4*)(hT + ((size_t)b * 128 + dt * 64 + d) * 1024 + jt * 64 + c4) = o;
    }
}

// ---------------------------------------------------------------------------
// out[b,i,d] = sum_j sigmoid(si[i]+sj[j]+ab)*adj[b,i,j]*h[b,j,d]  (opt relu)
// grid (8 i-tiles, 8 b), 256 threads (4 waves). MFMA bf16, fp32 acc.
__global__ __launch_bounds__(256) void gnn_agg(
    const float* __restrict__ adj, const unsigned short* __restrict__ hT,
    const float* __restrict__ si, const float* __restrict__ sj,
    const float* __restrict__ abp, float* __restrict__ out, int RELU)
{
    __shared__ __align__(16) unsigned short Alds[128 * 40];  // [i][j] stride 40
    __shared__ __align__(16) unsigned short Blds[128 * 40];  // [d][j] stride 40
    const int b = blockIdx.y, it = blockIdx.x;
    const int i0 = it * 128;
    const int tid = threadIdx.x, lane = tid & 63, w = tid >> 6;
    const int quad = lane >> 4, col = lane & 15;
    const float ab = abp[0];
    const float* adjb = adj + (size_t)b * 1024 * 1024;
    const unsigned short* hTb = hT + (size_t)b * 128 * 1024;
    const float* sjb = sj + b * 1024;

    f32x4 acc[2][8] = {};
    const int sr = tid >> 1, sh = (tid & 1) * 16;
    const float sii = si[b * 1024 + i0 + sr] + ab;

    for (int j0 = 0; j0 < 1024; j0 += 32) {
        __syncthreads();
        {   // stage A: att tile 128x32 (computed on the fly)
            const float* ar = adjb + (size_t)(i0 + sr) * 1024 + j0 + sh;
            unsigned short* al = Alds + sr * 40 + sh;
#pragma unroll
            for (int q = 0; q < 16; q += 4) {
                f32x4 av = *(const f32x4*)(ar + q);
#pragma unroll
                for (int e = 0; e < 4; ++e) {
                    float s = sigm(sii + sjb[j0 + sh + q + e]) * av[e];
                    al[q + e] = bf16_of(s);
                }
            }
        }
        {   // stage B: hT rows d=0..127, 32 j's
            const unsigned short* bsrc = hTb + (size_t)sr * 1024 + j0 + sh;
            unsigned short* bl = Blds + sr * 40 + sh;
            *(short8*)&bl[0] = *(const short8*)&bsrc[0];
            *(short8*)&bl[8] = *(const short8*)&bsrc[8];
        }
        __syncthreads();
        short8 bfrag[8];
#pragma unroll
        for (int nt = 0; nt < 8; ++nt)
            bfrag[nt] = *(const short8*)&Blds[(nt * 16 + col) * 40 + quad * 8];
#pragma unroll
        for (int mt = 0; mt < 2; ++mt) {
            short8 af = *(const short8*)&Alds[((w * 2 + mt) * 16 + col) * 40 + quad * 8];
#pragma unroll
            for (int nt = 0; nt < 8; ++nt)
                acc[mt][nt] = mfma16(af, bfrag[nt], acc[mt][nt]);
        }
    }
#pragma unroll
    for (int mt = 0; mt < 2; ++mt) {
        const int ibase = i0 + (w * 2 + mt) * 16 + quad * 4;
#pragma unroll
        for (int nt = 0; nt < 8; ++nt) {
            const int d = nt * 16 + col;
#pragma unroll
            for (int r = 0; r < 4; ++r) {
                float v = acc[mt][nt][r];
                if (RELU) v = fmaxf(v, 0.f);
                out[((size_t)b * 1024 + ibase + r) * 128 + d] = v;
            }
        }
    }
}

// ---------------------------------------------------------------------------
// xw[t][r][b] = tmp[b*1024+t][r] + bih[r] + bhh[r]
__global__ __launch_bounds__(256) void permute_xw(
    const float* __restrict__ tmp, const float* __restrict__ bih,
    const float* __restrict__ bhh, float* __restrict__ xw)
{
    const int idx = blockIdx.x * 256 + threadIdx.x;  // < 4194304
    const int bb = idx & 7;
    const int r = (idx >> 3) & 511;
    const int t = idx >> 12;
    xw[idx] = tmp[((size_t)bb * 1024 + t) * 512 + r] + bih[r] + bhh[r];
}

// ---------------------------------------------------------------------------
// Persistent single-workgroup LSTM layer.
// xw: [1024][512][8] precomputed x@Wih^T + bih + bhh.  Whh: [512][128] fp32.
// out: [8][1024][128] hidden states (fp32).
// 512 threads = 8 waves; wave w owns MFMA rows for h-tile [w*16, w*16+16) of
// all 4 gates. After MFMA, gates round-trip through per-wave LDS scratch so
// EVERY lane owns 2 (batch,h) pairs for the transcendental epilogue (halves
// trans-pipe pressure vs col<8-only). xw is register-prefetched at depth 2;
// the per-step barrier is a raw lgkmcnt-only s_barrier so the prefetch's
// vmcnt stays outstanding across it (__syncthreads would drain vmcnt(0)).
__global__ __launch_bounds__(512) void lstm_kernel(
    const float* __restrict__ xw, const float* __restrict__ Whh,
    float* __restrict__ out)
{
    __shared__ __align__(16) unsigned short H[2][16 * 136];  // [buf][b(16)][k(128)+pad]
    __shared__ __align__(16) float Gs[8 * 544];              // per-wave [b(8)][h(16)][g(4)] stride 68
    const int tid = threadIdx.x;
    const int lane = tid & 63;
    const int w = tid >> 6;        // wave 0..7
    const int quad = lane >> 4;    // 0..3
    const int col = lane & 15;     // MFMA n (batch if <8)
    const int hl = lane >> 2;      // 0..15: owned h within wave tile
    const int b0 = (lane & 3) * 2; // owned batch pair {b0, b0+1}
    const int hh = w * 16 + hl;    // global h index owned by this lane

    for (int i = tid; i < 2 * 16 * 136; i += 512) (&H[0][0])[i] = 0;

    // A-fragments: afr[g][c] covers rows g*128 + w*16 + (lane&15), k = c*32+quad*8..+8
    short8 afr[4][4];
#pragma unroll
    for (int g = 0; g < 4; ++g) {
        const int row = g * 128 + w * 16 + col;
#pragma unroll
        for (int c = 0; c < 4; ++c) {
            const float* src = Whh + row * 128 + c * 32 + quad * 8;
            short8 v;
#pragma unroll
            for (int j = 0; j < 8; ++j) v[j] = (short)bf16_of(src[j]);
            afr[g][c] = v;
        }
    }

    // prefetch xw for t=0,1 (depth-2 register pipeline)
    f32x2 pf[2][4];
#pragma unroll
    for (int s = 0; s < 2; ++s)
#pragma unroll
        for (int g = 0; g < 4; ++g)
            pf[s][g] = *(const f32x2*)&xw[((s * 512 + g * 128 + hh) << 3) + b0];

    float cst[2] = {0.f, 0.f};
    __syncthreads();

    for (int t = 0; t < 1024; ++t) {
        const int cur = t & 1;
        // B-fragments from LDS h
        short8 bfr[4];
#pragma unroll
        for (int c = 0; c < 4; ++c)
            bfr[c] = *(const short8*)&H[cur][col * 136 + c * 32 + quad * 8];
        f32x4 acc[4] = {};
#pragma unroll
        for (int c = 0; c < 4; ++c)
#pragma unroll
            for (int g = 0; g < 4; ++g)
                acc[g] = mfma16(afr[g][c], bfr[c], acc[g]);

        // intra-wave gate exchange: MFMA C-layout -> per-lane (b,h) pairs
        if (col < 8) {
            float* gb = &Gs[w * 544 + col * 68 + quad * 16];
#pragma unroll
            for (int i = 0; i < 4; ++i)
#pragma unroll
                for (int g = 0; g < 4; ++g)
                    gb[i * 4 + g] = acc[g][i];
        }
        const float* rb = &Gs[w * 544 + hl * 4];
        f32x4 gv0 = *(const f32x4*)&rb[b0 * 68];
        f32x4 gv1 = *(const f32x4*)&rb[(b0 + 1) * 68];

        // consume prefetched xw; immediately re-arm the slot for t+2
        f32x2 xv[4];
#pragma unroll
        for (int g = 0; g < 4; ++g) xv[g] = pf[cur][g];
        {
            const int t2 = (t + 2 < 1024) ? t + 2 : 1023;
#pragma unroll
            for (int g = 0; g < 4; ++g)
                pf[cur][g] = *(const f32x2*)&xw[((t2 * 512 + g * 128 + hh) << 3) + b0];
        }

        // epilogue: 2 (b,h) pairs per lane
        unsigned short* Hn = &H[cur ^ 1][0];
#pragma unroll
        for (int k = 0; k < 2; ++k) {
            f32x4 gv = k ? gv1 : gv0;
            float ig = sigm(gv[0] + xv[0][k]);
            float fg = sigm(gv[1] + xv[1][k]);
            float gg = tanh_f(gv[2] + xv[2][k]);
            float og = sigm(gv[3] + xv[3][k]);
            float c2 = fg * cst[k] + ig * gg;
            cst[k] = c2;
            float hv = og * tanh_f(c2);
            Hn[(b0 + k) * 136 + hh] = bf16_of(hv);
            out[((size_t)(b0 + k) * 1024 + t) * 128 + hh] = hv;
        }
        // lgkm-only barrier: H/G writes drained, vmcnt (xw prefetch) left in flight
        asm volatile("s_waitcnt lgkmcnt(0)\n\ts_barrier" ::: "memory");
    }
}

// ---------------------------------------------------------------------------
extern "C" void kernel_launch(void* const* d_in, const int* in_sizes, int n_in,
                              void* d_out, int out_size, void* d_ws, size_t ws_size,
                              hipStream_t stream)
{
    (void)in_sizes; (void)n_in; (void)out_size; (void)ws_size;
    const float* nf    = (const float*)d_in[0];
    const float* adj   = (const float*)d_in[1];
    const float* g1W   = (const float*)d_in[3];
    const float* g1b   = (const float*)d_in[4];
    const float* g1aW  = (const float*)d_in[5];
    const float* g1ab  = (const float*)d_in[6];
    const float* g2W   = (const float*)d_in[7];
    const float* g2b   = (const float*)d_in[8];
    const float* g2aW  = (const float*)d_in[9];
    const float* g2ab  = (const float*)d_in[10];
    const float* g3W   = (const float*)d_in[11];
    const float* g3b   = (const float*)d_in[12];
    const float* g3aW  = (const float*)d_in[13];
    const float* g3ab  = (const float*)d_in[14];
    const float* l0Wih = (const float*)d_in[15];
    const float* l0Whh = (const float*)d_in[16];
    const float* l0bih = (const float*)d_in[17];
    const float* l0bhh = (const float*)d_in[18];
    const float* l1Wih = (const float*)d_in[19];
    const float* l1Whh = (const float*)d_in[20];
    const float* l1bih = (const float*)d_in[21];
    const float* l1bhh = (const float*)d_in[22];
    const float* opW1 = (const float*)d_in[23];
    const float* opb1 = (const float*)d_in[24];
    const float* opW2 = (const float*)d_in[25];
    const float* opb2 = (const float*)d_in[26];
    const float* paW1 = (const float*)d_in[27];
    const float* pab1 = (const float*)d_in[28];
    const float* paW2 = (const float*)d_in[29];
    const float* pab2 = (const float*)d_in[30];
    const float* skW1 = (const float*)d_in[31];
    const float* skb1 = (const float*)d_in[32];
    const float* skW2 = (const float*)d_in[33];
    const float* skb2 = (const float*)d_in[34];
    const float* noW1 = (const float*)d_in[35];
    const float* nob1 = (const float*)d_in[36];
    const float* noW2 = (const float*)d_in[37];
    const float* nob2 = (const float*)d_in[38];

    float* out = (float*)d_out;
    float* ws = (float*)d_ws;
    float* bufH  = ws;                     // 1048576
    float* bufX  = ws + 1048576;           // 1048576
    float* bufH3 = ws + 2097152;           // 1048576
    unsigned short* bufT = (unsigned short*)(ws + 3145728);  // 1048576 shorts
    float* siB = ws + 3670016;             // 8192
    float* sjB = ws + 3678208;             // 8192
    float* tmp = ws + 3686400;             // 4194304
    float* xw  = ws + 7880704;             // 4194304 (end: 48.3 MB)

    auto gemm = [&](const float* A, const float* B, const float* bias, float* C,
                    int M, int N, int K, int BT, int RELU) {
        dim3 g(N / 64, M / 64);
        gemm_f32<<<g, dim3(256), 0, stream>>>(A, B, bias, C, M, N, K, BT, RELU);
    };

    // ---- GNN layer 1 (din=64, relu)
    gemm(nf, g1W, g1b, bufH, 8192, 128, 64, 0, 0);
    sisj_kernel<<<2048, 256, 0, stream>>>(bufH, g1aW, siB, sjB);
    transpose_bf16_k<<<dim3(16, 2, 8), 256, 0, stream>>>(bufH, bufT);
    gnn_agg<<<dim3(8, 8), 256, 0, stream>>>(adj, bufT, siB, sjB, g1ab, bufX, 1);
    // ---- GNN layer 2 (relu)
    gemm(bufX, g2W, g2b, bufH, 8192, 128, 128, 0, 0);
    sisj_kernel<<<2048, 256, 0, stream>>>(bufH, g2aW, siB, sjB);
    transpose_bf16_k<<<dim3(16, 2, 8), 256, 0, stream>>>(bufH, bufT);
    gnn_agg<<<dim3(8, 8), 256, 0, stream>>>(adj, bufT, siB, sjB, g2ab, bufX, 1);
    // ---- GNN layer 3 (no relu) -> bufH3
    gemm(bufX, g3W, g3b, bufH, 8192, 128, 128, 0, 0);
    sisj_kernel<<<2048, 256, 0, stream>>>(bufH, g3aW, siB, sjB);
    transpose_bf16_k<<<dim3(16, 2, 8), 256, 0, stream>>>(bufH, bufT);
    gnn_agg<<<dim3(8, 8), 256, 0, stream>>>(adj, bufT, siB, sjB, g3ab, bufH3, 0);

    // ---- LSTM layer 0: lo0 = bufX
    gemm(bufH3, l0Wih, nullptr, tmp, 8192, 512, 128, 1, 0);
    permute_xw<<<16384, 256, 0, stream>>>(tmp, l0bih, l0bhh, xw);
    lstm_kernel<<<1, 512, 0, stream>>>(xw, l0Whh, bufX);
    // ---- LSTM layer 1: lo1 = tmp
    gemm(bufX, l1Wih, nullptr, tmp, 8192, 512, 128, 1, 0);
    permute_xw<<<16384, 256, 0, stream>>>(tmp, l1bih, l1bhh, xw);
    lstm_kernel<<<1, 512, 0, stream>>>(xw, l1Whh, tmp);

    // ---- heads (op, pa, sk from lo1=tmp; no from h3=bufH3)
    gemm(tmp, opW1, opb1, bufH, 8192, 128, 128, 0, 1);
    gemm(bufH, opW2, opb2, out + 0, 8192, 64, 128, 0, 0);
    gemm(tmp, paW1, pab1, bufH, 8192, 128, 128, 0, 1);
    gemm(bufH, paW2, pab2, out + 524288, 8192, 256, 128, 0, 0);
    gemm(tmp, skW1, skb1, bufH, 8192, 128, 128, 0, 1);
    gemm(bufH, skW2, skb2, out + 2621440, 8192, 128, 128, 0, 0);
    gemm(bufH3, noW1, nob1, bufH, 8192, 128, 128, 0, 1);
    gemm(bufH, noW2, nob2, out + 3670016, 8192, 64, 128, 0, 0);
}

// Round 3
// 2407.577 us; speedup vs baseline: 1.5425x; 1.5425x over previous
//
#include <hip/hip_runtime.h>

typedef __attribute__((ext_vector_type(8))) short short8;
typedef __attribute__((ext_vector_type(4))) float f32x4;
typedef __attribute__((ext_vector_type(2))) float f32x2;
typedef __attribute__((ext_vector_type(4))) unsigned short us4;

__device__ __forceinline__ unsigned short bf16_of(float f) {
    unsigned u = __builtin_bit_cast(unsigned, f);
    u += 0x7fffu + ((u >> 16) & 1u);   // RNE
    return (unsigned short)(u >> 16);
}
__device__ __forceinline__ float fexp2(float x) { return __builtin_amdgcn_exp2f(x); }
__device__ __forceinline__ float frcp(float x) { return __builtin_amdgcn_rcpf(x); }
__device__ __forceinline__ float sigm(float x) { return frcp(1.f + fexp2(-1.44269504f * x)); }
__device__ __forceinline__ float tanh_f(float x) {
    float e = fexp2(2.88539008f * x);   // e^(2x)
    return 1.f - 2.f * frcp(e + 1.f);
}
__device__ __forceinline__ f32x4 mfma16(short8 a, short8 b, f32x4 c) {
    return __builtin_amdgcn_mfma_f32_16x16x32_bf16(a, b, c, 0, 0, 0);
}
// DPP cross-lane within 16-lane rows. row_shr:8 -> lane i gets lane i-8
// (lanes 0-7 of each row: 0 via bound_ctrl). row_shl:8 -> lane i gets lane i+8.
__device__ __forceinline__ float dpp_shr8(float x) {
    return __builtin_bit_cast(float, __builtin_amdgcn_update_dpp(
        0, __builtin_bit_cast(int, x), 0x118, 0xF, 0xF, true));
}
__device__ __forceinline__ float dpp_shl8(float x) {
    return __builtin_bit_cast(float, __builtin_amdgcn_update_dpp(
        0, __builtin_bit_cast(int, x), 0x108, 0xF, 0xF, true));
}

// ---------------------------------------------------------------------------
// Generic fp32 GEMM: C[M,N] = A[M,K] @ B (+bias) (optional relu)
// BT=0: B is [K,N] row-major.  BT=1: B is [N,K] row-major (i.e. use B^T).
__global__ __launch_bounds__(256) void gemm_f32(
    const float* __restrict__ A, const float* __restrict__ B,
    const float* __restrict__ bias, float* __restrict__ C,
    int M, int N, int K, int BT, int RELU)
{
    __shared__ float As[64][33];
    __shared__ float Bs[32][68];
    const int tid = threadIdx.x;
    const int tx = tid & 15, ty = tid >> 4;
    const int m0 = blockIdx.y * 64, n0 = blockIdx.x * 64;
    float acc[4][4];
#pragma unroll
    for (int i = 0; i < 4; ++i)
#pragma unroll
        for (int j = 0; j < 4; ++j) acc[i][j] = 0.f;

    for (int k0 = 0; k0 < K; k0 += 32) {
        __syncthreads();
        {   // stage A 64x32
            const int r = tid >> 2, kk = (tid & 3) * 8;
            const float* src = A + (size_t)(m0 + r) * K + k0 + kk;
            f32x4 v0 = *(const f32x4*)src;
            f32x4 v1 = *(const f32x4*)(src + 4);
#pragma unroll
            for (int e = 0; e < 4; ++e) { As[r][kk + e] = v0[e]; As[r][kk + 4 + e] = v1[e]; }
        }
        if (!BT) {  // stage B 32x64
            const int kk = tid >> 3, nn = (tid & 7) * 8;
            const float* src = B + (size_t)(k0 + kk) * N + n0 + nn;
            f32x4 v0 = *(const f32x4*)src;
            f32x4 v1 = *(const f32x4*)(src + 4);
#pragma unroll
            for (int e = 0; e < 4; ++e) { Bs[kk][nn + e] = v0[e]; Bs[kk][nn + 4 + e] = v1[e]; }
        } else {    // B given [N,K]: transpose-stage
            const int n = tid >> 2, kk = (tid & 3) * 8;
            const float* src = B + (size_t)(n0 + n) * K + k0 + kk;
            f32x4 v0 = *(const f32x4*)src;
            f32x4 v1 = *(const f32x4*)(src + 4);
#pragma unroll
            for (int e = 0; e < 4; ++e) { Bs[kk + e][n] = v0[e]; Bs[kk + 4 + e][n] = v1[e]; }
        }
        __syncthreads();
#pragma unroll 8
        for (int k = 0; k < 32; ++k) {
            float a0 = As[ty * 4 + 0][k], a1 = As[ty * 4 + 1][k];
            float a2 = As[ty * 4 + 2][k], a3 = As[ty * 4 + 3][k];
            f32x4 bv = *(const f32x4*)&Bs[k][tx * 4];
#pragma unroll
            for (int j = 0; j < 4; ++j) {
                acc[0][j] += a0 * bv[j]; acc[1][j] += a1 * bv[j];
                acc[2][j] += a2 * bv[j]; acc[3][j] += a3 * bv[j];
            }
        }
    }
    f32x4 bv = {};
    if (bias != nullptr) bv = *(const f32x4*)&bias[n0 + tx * 4];
#pragma unroll
    for (int i = 0; i < 4; ++i) {
        f32x4 res = {};
#pragma unroll
        for (int j = 0; j < 4; ++j) {
            float v = acc[i][j] + bv[j];
            if (RELU) v = fmaxf(v, 0.f);
            res[j] = v;
        }
        *(f32x4*)&C[(size_t)(m0 + ty * 4 + i) * N + n0 + tx * 4] = res;
    }
}

// ---------------------------------------------------------------------------
// si[b,n] = h[b,n,:]·aW[128:256],  sj[b,n] = h[b,n,:]·aW[0:128]
__global__ __launch_bounds__(256) void sisj_kernel(
    const float* __restrict__ h, const float* __restrict__ aW,
    float* __restrict__ si, float* __restrict__ sj)
{
    const int tid = threadIdx.x, lane = tid & 63, w = tid >> 6;
    const int row = blockIdx.x * 4 + w;  // 0..8191
    f32x2 hv = *(const f32x2*)(h + (size_t)row * 128 + lane * 2);
    f32x2 w1 = *(const f32x2*)&aW[lane * 2];
    f32x2 w2 = *(const f32x2*)&aW[128 + lane * 2];
    float sjp = hv[0] * w1[0] + hv[1] * w1[1];
    float sip = hv[0] * w2[0] + hv[1] * w2[1];
#pragma unroll
    for (int o = 32; o > 0; o >>= 1) {
        sjp += __shfl_xor(sjp, o);
        sip += __shfl_xor(sip, o);
    }
    if (lane == 0) { si[row] = sip; sj[row] = sjp; }
}

// ---------------------------------------------------------------------------
// hT[b][d][j] = bf16(h[b][j][d])   (for MFMA B staging)
__global__ __launch_bounds__(256) void transpose_bf16_k(
    const float* __restrict__ h, unsigned short* __restrict__ hT)
{
    __shared__ float t[64][65];
    const int b = blockIdx.z, jt = blockIdx.x, dt = blockIdx.y;
    const int tid = threadIdx.x;
    const int r = tid >> 4, c4 = (tid & 15) * 4;
#pragma unroll
    for (int rr = 0; rr < 4; ++rr) {
        const int j = rr * 16 + r;
        f32x4 v = *(const f32x4*)(h + ((size_t)b * 1024 + jt * 64 + j) * 128 + dt * 64 + c4);
#pragma unroll
        for (int e = 0; e < 4; ++e) t[j][c4 + e] = v[e];
    }
    __syncthreads();
#pragma unroll
    for (int rr = 0; rr < 4; ++rr) {
        const int d = rr * 16 + r;
        us4 o;
#pragma unroll
        for (int e = 0; e < 4; ++e) o[e] = bf16_of(t[c4 + e][d]);
        *(us4*)(hT + ((size_t)b * 128 + dt * 64 + d) * 1024 + jt * 64 + c4) = o;
    }
}

// ---------------------------------------------------------------------------
// out[b,i,d] = sum_j sigmoid(si[i]+sj[j]+ab)*adj[b,i,j]*h[b,j,d]  (opt relu)
__global__ __launch_bounds__(256) void gnn_agg(
    const float* __restrict__ adj, const unsigned short* __restrict__ hT,
    const float* __restrict__ si, const float* __restrict__ sj,
    const float* __restrict__ abp, float* __restrict__ out, int RELU)
{
    __shared__ __align__(16) unsigned short Alds[128 * 40];  // [i][j] stride 40
    __shared__ __align__(16) unsigned short Blds[128 * 40];  // [d][j] stride 40
    const int b = blockIdx.y, it = blockIdx.x;
    const int i0 = it * 128;
    const int tid = threadIdx.x, lane = tid & 63, w = tid >> 6;
    const int quad = lane >> 4, col = lane & 15;
    const float ab = abp[0];
    const float* adjb = adj + (size_t)b * 1024 * 1024;
    const unsigned short* hTb = hT + (size_t)b * 128 * 1024;
    const float* sjb = sj + b * 1024;

    f32x4 acc[2][8] = {};
    const int sr = tid >> 1, sh = (tid & 1) * 16;
    const float sii = si[b * 1024 + i0 + sr] + ab;

    for (int j0 = 0; j0 < 1024; j0 += 32) {
        __syncthreads();
        {   // stage A: att tile 128x32 (computed on the fly)
            const float* ar = adjb + (size_t)(i0 + sr) * 1024 + j0 + sh;
            unsigned short* al = Alds + sr * 40 + sh;
#pragma unroll
            for (int q = 0; q < 16; q += 4) {
                f32x4 av = *(const f32x4*)(ar + q);
#pragma unroll
                for (int e = 0; e < 4; ++e) {
                    float s = sigm(sii + sjb[j0 + sh + q + e]) * av[e];
                    al[q + e] = bf16_of(s);
                }
            }
        }
        {   // stage B: hT rows d=0..127, 32 j's
            const unsigned short* bsrc = hTb + (size_t)sr * 1024 + j0 + sh;
            unsigned short* bl = Blds + sr * 40 + sh;
            *(short8*)&bl[0] = *(const short8*)&bsrc[0];
            *(short8*)&bl[8] = *(const short8*)&bsrc[8];
        }
        __syncthreads();
        short8 bfrag[8];
#pragma unroll
        for (int nt = 0; nt < 8; ++nt)
            bfrag[nt] = *(const short8*)&Blds[(nt * 16 + col) * 40 + quad * 8];
#pragma unroll
        for (int mt = 0; mt < 2; ++mt) {
            short8 af = *(const short8*)&Alds[((w * 2 + mt) * 16 + col) * 40 + quad * 8];
#pragma unroll
            for (int nt = 0; nt < 8; ++nt)
                acc[mt][nt] = mfma16(af, bfrag[nt], acc[mt][nt]);
        }
    }
#pragma unroll
    for (int mt = 0; mt < 2; ++mt) {
        const int ibase = i0 + (w * 2 + mt) * 16 + quad * 4;
#pragma unroll
        for (int nt = 0; nt < 8; ++nt) {
            const int d = nt * 16 + col;
#pragma unroll
            for (int r = 0; r < 4; ++r) {
                float v = acc[mt][nt][r];
                if (RELU) v = fmaxf(v, 0.f);
                out[((size_t)b * 1024 + ibase + r) * 128 + d] = v;
            }
        }
    }
}

// ---------------------------------------------------------------------------
// xw layout for the LSTM pack-domain: xw[((t*4 + pr)*8 + b)*128 + h]
//   = tmp[b*1024+t][pr*128+h] + bih + bhh,  pr in {0:i,1:f,2:g,3:o}
__global__ __launch_bounds__(256) void permute_xw(
    const float* __restrict__ tmp, const float* __restrict__ bih,
    const float* __restrict__ bhh, float* __restrict__ xw)
{
    const int idx = blockIdx.x * 256 + threadIdx.x;  // < 4194304
    const int h = idx & 127;
    const int b = (idx >> 7) & 7;
    const int pr = (idx >> 10) & 3;
    const int t = idx >> 12;
    const int r = pr * 128 + h;
    xw[idx] = tmp[((size_t)b * 1024 + t) * 512 + r] + bih[r] + bhh[r];
}

// ---------------------------------------------------------------------------
// Persistent single-workgroup LSTM layer (8 waves, 1 CU).
// Per step: wave w computes gate rows {g*128 + w*16 .. +16} (16 MFMA).
// Epilogue: all 4 gates via tanh (sigm(x)=0.5*(1+tanh(x/2))) with DPP
// row_shr/shl:8 packing (i|f), (g|o), and c-row pairs -> 20 trans wave-ops
// (vs 40 unpacked), no LDS round-trip. xw register-prefetched at depth 2
// with static indices (loop unrolled x2). Barrier = s_waitcnt lgkmcnt(0) +
// s_barrier via builtins (no inline asm: a "memory"-clobber asm gets
// mayLoad/mayStore and forces a vmcnt(0) drain — the round-2 regression).
template <int CUR>
__device__ __forceinline__ void lstm_step(
    unsigned short* Hc, unsigned short* Hn, const short8 afr[4][4],
    f32x4 xv0, f32x4 xv1, float* cst, float* __restrict__ out,
    int t, int col, int quad, int h4, int b)
{
    short8 bfr[4];
#pragma unroll
    for (int c = 0; c < 4; ++c)
        bfr[c] = *(const short8*)&Hc[col * 136 + c * 32 + quad * 8];
    f32x4 acc[4] = {};
#pragma unroll
    for (int c = 0; c < 4; ++c)
#pragma unroll
        for (int g = 0; g < 4; ++g)
            acc[g] = mfma16(afr[g][c], bfr[c], acc[g]);

    const bool lo = (col < 8);
    // pack-domain trans: cols0-7 = {i,g}, cols8-15 = {f,o} (shifted from 0-7)
    float t0[4], t1[4];
#pragma unroll
    for (int i = 0; i < 4; ++i) {
        float P0 = 0.5f * ((lo ? acc[0][i] : dpp_shr8(acc[1][i])) + xv0[i]);
        float P1r = (lo ? acc[2][i] : dpp_shr8(acc[3][i])) + xv1[i];
        float P1 = lo ? P1r : 0.5f * P1r;
        t0[i] = tanh_f(P0);   // cols0-7: tanh(zi/2); cols8-15: tanh(zf/2)
        t1[i] = tanh_f(P1);   // cols0-7: tanh(zg);   cols8-15: tanh(zo/2)
    }
    float c2[4], og[4];
#pragma unroll
    for (int i = 0; i < 4; ++i) {
        float ig = 0.5f + 0.5f * t0[i];
        float fg = 0.5f + 0.5f * dpp_shl8(t0[i]);
        float gg = t1[i];
        og[i] = 0.5f + 0.5f * dpp_shl8(t1[i]);
        c2[i] = fg * cst[i] + ig * gg;
        cst[i] = c2[i];
    }
    // tanh(c2): pack row pairs into full lane width
    float pc0 = lo ? c2[0] : dpp_shr8(c2[1]);
    float pc1 = lo ? c2[2] : dpp_shr8(c2[3]);
    float tc0 = tanh_f(pc0), tc1 = tanh_f(pc1);
    float th[4] = {tc0, dpp_shl8(tc0), tc1, dpp_shl8(tc1)};
    float hv[4];
#pragma unroll
    for (int i = 0; i < 4; ++i) hv[i] = og[i] * th[i];

    if (lo) {
        us4 hb;
#pragma unroll
        for (int i = 0; i < 4; ++i) hb[i] = bf16_of(hv[i]);
        *(us4*)&Hn[b * 136 + h4] = hb;
        f32x4 res = {hv[0], hv[1], hv[2], hv[3]};
        *(f32x4*)(out + ((size_t)b * 1024 + t) * 128 + h4) = res;
    }
    // lgkmcnt(0)-only barrier: LDS drained, vmcnt (xw prefetch + out stores)
    // stays outstanding.  0xC07F = vmcnt(63) expcnt(7) lgkmcnt(0).
    __builtin_amdgcn_s_waitcnt(0xC07F);
    __builtin_amdgcn_s_barrier();
}

__global__ __launch_bounds__(512) void lstm_kernel(
    const float* __restrict__ xw, const float* __restrict__ Whh,
    float* __restrict__ out)
{
    __shared__ __align__(16) unsigned short H[2][16 * 136];
    const int tid = threadIdx.x;
    const int lane = tid & 63;
    const int w = tid >> 6;
    const int quad = lane >> 4;
    const int col = lane & 15;
    const int b = col & 7;
    const int prA = col >> 3;          // 0: this lane's pack cols carry i,g; 1: f,o
    const int h4 = w * 16 + quad * 4;  // global h base owned in epilogue

    for (int i = tid; i < 2 * 16 * 136; i += 512) (&H[0][0])[i] = 0;

    // A-fragments: afr[g][c] = Whh rows g*128 + w*16 + col, k = c*32+quad*8..+8
    short8 afr[4][4];
#pragma unroll
    for (int g = 0; g < 4; ++g) {
        const int row = g * 128 + w * 16 + col;
#pragma unroll
        for (int c = 0; c < 4; ++c) {
            const float* src = Whh + row * 128 + c * 32 + quad * 8;
            short8 v;
#pragma unroll
            for (int j = 0; j < 8; ++j) v[j] = (short)bf16_of(src[j]);
            afr[g][c] = v;
        }
    }

    // xw pointer for this lane's pack slots (pr = prA for P0, 2+prA for P1)
    const float* xp = xw + (size_t)((prA * 8 + b) * 128 + h4);
    f32x4 p0a = *(const f32x4*)(xp);           // t=0, P0
    f32x4 p1a = *(const f32x4*)(xp + 2048);    // t=0, P1
    f32x4 p0b = *(const f32x4*)(xp + 4096);    // t=1, P0
    f32x4 p1b = *(const f32x4*)(xp + 6144);    // t=1, P1
    xp += 8192;                                 // -> t=2

    float cst[4] = {0.f, 0.f, 0.f, 0.f};
    __syncthreads();

    for (int t = 0; t < 1024; t += 2) {
        const float* xr = (t == 1022) ? xp - 8192 : xp;  // avoid OOB prefetch
        {
            f32x4 xv0 = p0a, xv1 = p1a;
            p0a = *(const f32x4*)(xr);          // t+2
            p1a = *(const f32x4*)(xr + 2048);
            lstm_step<0>(&H[0][0], &H[1][0], afr, xv0, xv1, cst, out, t, col, quad, h4, b);
        }
        {
            f32x4 xv0 = p0b, xv1 = p1b;
            p0b = *(const f32x4*)(xr + 4096);   // t+3
            p1b = *(const f32x4*)(xr + 6144);
            lstm_step<1>(&H[1][0], &H[0][0], afr, xv0, xv1, cst, out, t + 1, col, quad, h4, b);
        }
        xp += 8192;
    }
}

// ---------------------------------------------------------------------------
extern "C" void kernel_launch(void* const* d_in, const int* in_sizes, int n_in,
                              void* d_out, int out_size, void* d_ws, size_t ws_size,
                              hipStream_t stream)
{
    (void)in_sizes; (void)n_in; (void)out_size; (void)ws_size;
    const float* nf    = (const float*)d_in[0];
    const float* adj   = (const float*)d_in[1];
    const float* g1W   = (const float*)d_in[3];
    const float* g1b   = (const float*)d_in[4];
    const float* g1aW  = (const float*)d_in[5];
    const float* g1ab  = (const float*)d_in[6];
    const float* g2W   = (const float*)d_in[7];
    const float* g2b   = (const float*)d_in[8];
    const float* g2aW  = (const float*)d_in[9];
    const float* g2ab  = (const float*)d_in[10];
    const float* g3W   = (const float*)d_in[11];
    const float* g3b   = (const float*)d_in[12];
    const float* g3aW  = (const float*)d_in[13];
    const float* g3ab  = (const float*)d_in[14];
    const float* l0Wih = (const float*)d_in[15];
    const float* l0Whh = (const float*)d_in[16];
    const float* l0bih = (const float*)d_in[17];
    const float* l0bhh = (const float*)d_in[18];
    const float* l1Wih = (const float*)d_in[19];
    const float* l1Whh = (const float*)d_in[20];
    const float* l1bih = (const float*)d_in[21];
    const float* l1bhh = (const float*)d_in[22];
    const float* opW1 = (const float*)d_in[23];
    const float* opb1 = (const float*)d_in[24];
    const float* opW2 = (const float*)d_in[25];
    const float* opb2 = (const float*)d_in[26];
    const float* paW1 = (const float*)d_in[27];
    const float* pab1 = (const float*)d_in[28];
    const float* paW2 = (const float*)d_in[29];
    const float* pab2 = (const float*)d_in[30];
    const float* skW1 = (const float*)d_in[31];
    const float* skb1 = (const float*)d_in[32];
    const float* skW2 = (const float*)d_in[33];
    const float* skb2 = (const float*)d_in[34];
    const float* noW1 = (const float*)d_in[35];
    const float* nob1 = (const float*)d_in[36];
    const float* noW2 = (const float*)d_in[37];
    const float* nob2 = (const float*)d_in[38];

    float* out = (float*)d_out;
    float* ws = (float*)d_ws;
    float* bufH  = ws;                     // 1048576
    float* bufX  = ws + 1048576;           // 1048576
    float* bufH3 = ws + 2097152;           // 1048576
    unsigned short* bufT = (unsigned short*)(ws + 3145728);  // 1048576 shorts
    float* siB = ws + 3670016;             // 8192
    float* sjB = ws + 3678208;             // 8192
    float* tmp = ws + 3686400;             // 4194304
    float* xw  = ws + 7880704;             // 4194304 + 8192 slack

    auto gemm = [&](const float* A, const float* B, const float* bias, float* C,
                    int M, int N, int K, int BT, int RELU) {
        dim3 g(N / 64, M / 64);
        gemm_f32<<<g, dim3(256), 0, stream>>>(A, B, bias, C, M, N, K, BT, RELU);
    };

    // ---- GNN layer 1 (din=64, relu)
    gemm(nf, g1W, g1b, bufH, 8192, 128, 64, 0, 0);
    sisj_kernel<<<2048, 256, 0, stream>>>(bufH, g1aW, siB, sjB);
    transpose_bf16_k<<<dim3(16, 2, 8), 256, 0, stream>>>(bufH, bufT);
    gnn_agg<<<dim3(8, 8), 256, 0, stream>>>(adj, bufT, siB, sjB, g1ab, bufX, 1);
    // ---- GNN layer 2 (relu)
    gemm(bufX, g2W, g2b, bufH, 8192, 128, 128, 0, 0);
    sisj_kernel<<<2048, 256, 0, stream>>>(bufH, g2aW, siB, sjB);
    transpose_bf16_k<<<dim3(16, 2, 8), 256, 0, stream>>>(bufH, bufT);
    gnn_agg<<<dim3(8, 8), 256, 0, stream>>>(adj, bufT, siB, sjB, g2ab, bufX, 1);
    // ---- GNN layer 3 (no relu) -> bufH3
    gemm(bufX, g3W, g3b, bufH, 8192, 128, 128, 0, 0);
    sisj_kernel<<<2048, 256, 0, stream>>>(bufH, g3aW, siB, sjB);
    transpose_bf16_k<<<dim3(16, 2, 8), 256, 0, stream>>>(bufH, bufT);
    gnn_agg<<<dim3(8, 8), 256, 0, stream>>>(adj, bufT, siB, sjB, g3ab, bufH3, 0);

    // ---- LSTM layer 0: lo0 = bufX
    gemm(bufH3, l0Wih, nullptr, tmp, 8192, 512, 128, 1, 0);
    permute_xw<<<16384, 256, 0, stream>>>(tmp, l0bih, l0bhh, xw);
    lstm_kernel<<<1, 512, 0, stream>>>(xw, l0Whh, bufX);
    // ---- LSTM layer 1: lo1 = tmp
    gemm(bufX, l1Wih, nullptr, tmp, 8192, 512, 128, 1, 0);
    permute_xw<<<16384, 256, 0, stream>>>(tmp, l1bih, l1bhh, xw);
    lstm_kernel<<<1, 512, 0, stream>>>(xw, l1Whh, tmp);

    // ---- heads (op, pa, sk from lo1=tmp; no from h3=bufH3)
    gemm(tmp, opW1, opb1, bufH, 8192, 128, 128, 0, 1);
    gemm(bufH, opW2, opb2, out + 0, 8192, 64, 128, 0, 0);
    gemm(tmp, paW1, pab1, bufH, 8192, 128, 128, 0, 1);
    gemm(bufH, paW2, pab2, out + 524288, 8192, 256, 128, 0, 0);
    gemm(tmp, skW1, skb1, bufH, 8192, 128, 128, 0, 1);
    gemm(bufH, skW2, skb2, out + 2621440, 8192, 128, 128, 0, 0);
    gemm(bufH3, noW1, nob1, bufH, 8192, 128, 128, 0, 1);
    gemm(bufH, noW2, nob2, out + 3670016, 8192, 64, 128, 0, 0);
}

// Round 4
// 1866.085 us; speedup vs baseline: 1.9902x; 1.2902x over previous
//
#include <hip/hip_runtime.h>

typedef __attribute__((ext_vector_type(8))) short short8;
typedef __attribute__((ext_vector_type(4))) float f32x4;
typedef __attribute__((ext_vector_type(2))) float f32x2;
typedef __attribute__((ext_vector_type(4))) unsigned short us4;

__device__ __forceinline__ unsigned short bf16_of(float f) {
    unsigned u = __builtin_bit_cast(unsigned, f);
    u += 0x7fffu + ((u >> 16) & 1u);   // RNE
    return (unsigned short)(u >> 16);
}
__device__ __forceinline__ float fexp2(float x) { return __builtin_amdgcn_exp2f(x); }
__device__ __forceinline__ float frcp(float x) { return __builtin_amdgcn_rcpf(x); }
__device__ __forceinline__ float sigm(float x) { return frcp(1.f + fexp2(-1.44269504f * x)); }
__device__ __forceinline__ float tanh_f(float x) {
    float e = fexp2(2.88539008f * x);   // e^(2x)
    return 1.f - 2.f * frcp(e + 1.f);
}
__device__ __forceinline__ f32x4 mfma16(short8 a, short8 b, f32x4 c) {
    return __builtin_amdgcn_mfma_f32_16x16x32_bf16(a, b, c, 0, 0, 0);
}
// DPP cross-lane within 16-lane rows. row_shr:8 -> lane i gets lane i-8
// (lanes 0-7 of each row: 0 via bound_ctrl). row_shl:8 -> lane i gets lane i+8.
__device__ __forceinline__ float dpp_shr8(float x) {
    return __builtin_bit_cast(float, __builtin_amdgcn_update_dpp(
        0, __builtin_bit_cast(int, x), 0x118, 0xF, 0xF, true));
}
__device__ __forceinline__ float dpp_shl8(float x) {
    return __builtin_bit_cast(float, __builtin_amdgcn_update_dpp(
        0, __builtin_bit_cast(int, x), 0x108, 0xF, 0xF, true));
}

// ---------------------------------------------------------------------------
// Generic fp32 GEMM: C[M,N] = A[M,K] @ B (+bias) (optional relu)
// BT=0: B is [K,N] row-major.  BT=1: B is [N,K] row-major (i.e. use B^T).
__global__ __launch_bounds__(256) void gemm_f32(
    const float* __restrict__ A, const float* __restrict__ B,
    const float* __restrict__ bias, float* __restrict__ C,
    int M, int N, int K, int BT, int RELU)
{
    __shared__ float As[64][33];
    __shared__ float Bs[32][68];
    const int tid = threadIdx.x;
    const int tx = tid & 15, ty = tid >> 4;
    const int m0 = blockIdx.y * 64, n0 = blockIdx.x * 64;
    float acc[4][4];
#pragma unroll
    for (int i = 0; i < 4; ++i)
#pragma unroll
        for (int j = 0; j < 4; ++j) acc[i][j] = 0.f;

    for (int k0 = 0; k0 < K; k0 += 32) {
        __syncthreads();
        {   // stage A 64x32
            const int r = tid >> 2, kk = (tid & 3) * 8;
            const float* src = A + (size_t)(m0 + r) * K + k0 + kk;
            f32x4 v0 = *(const f32x4*)src;
            f32x4 v1 = *(const f32x4*)(src + 4);
#pragma unroll
            for (int e = 0; e < 4; ++e) { As[r][kk + e] = v0[e]; As[r][kk + 4 + e] = v1[e]; }
        }
        if (!BT) {  // stage B 32x64
            const int kk = tid >> 3, nn = (tid & 7) * 8;
            const float* src = B + (size_t)(k0 + kk) * N + n0 + nn;
            f32x4 v0 = *(const f32x4*)src;
            f32x4 v1 = *(const f32x4*)(src + 4);
#pragma unroll
            for (int e = 0; e < 4; ++e) { Bs[kk][nn + e] = v0[e]; Bs[kk][nn + 4 + e] = v1[e]; }
        } else {    // B given [N,K]: transpose-stage
            const int n = tid >> 2, kk = (tid & 3) * 8;
            const float* src = B + (size_t)(n0 + n) * K + k0 + kk;
            f32x4 v0 = *(const f32x4*)src;
            f32x4 v1 = *(const f32x4*)(src + 4);
#pragma unroll
            for (int e = 0; e < 4; ++e) { Bs[kk + e][n] = v0[e]; Bs[kk + 4 + e][n] = v1[e]; }
        }
        __syncthreads();
#pragma unroll 8
        for (int k = 0; k < 32; ++k) {
            float a0 = As[ty * 4 + 0][k], a1 = As[ty * 4 + 1][k];
            float a2 = As[ty * 4 + 2][k], a3 = As[ty * 4 + 3][k];
            f32x4 bv = *(const f32x4*)&Bs[k][tx * 4];
#pragma unroll
            for (int j = 0; j < 4; ++j) {
                acc[0][j] += a0 * bv[j]; acc[1][j] += a1 * bv[j];
                acc[2][j] += a2 * bv[j]; acc[3][j] += a3 * bv[j];
            }
        }
    }
    f32x4 bv = {};
    if (bias != nullptr) bv = *(const f32x4*)&bias[n0 + tx * 4];
#pragma unroll
    for (int i = 0; i < 4; ++i) {
        f32x4 res = {};
#pragma unroll
        for (int j = 0; j < 4; ++j) {
            float v = acc[i][j] + bv[j];
            if (RELU) v = fmaxf(v, 0.f);
            res[j] = v;
        }
        *(f32x4*)&C[(size_t)(m0 + ty * 4 + i) * N + n0 + tx * 4] = res;
    }
}

// ---------------------------------------------------------------------------
// si[b,n] = h[b,n,:]·aW[128:256],  sj[b,n] = h[b,n,:]·aW[0:128]
__global__ __launch_bounds__(256) void sisj_kernel(
    const float* __restrict__ h, const float* __restrict__ aW,
    float* __restrict__ si, float* __restrict__ sj)
{
    const int tid = threadIdx.x, lane = tid & 63, w = tid >> 6;
    const int row = blockIdx.x * 4 + w;  // 0..8191
    f32x2 hv = *(const f32x2*)(h + (size_t)row * 128 + lane * 2);
    f32x2 w1 = *(const f32x2*)&aW[lane * 2];
    f32x2 w2 = *(const f32x2*)&aW[128 + lane * 2];
    float sjp = hv[0] * w1[0] + hv[1] * w1[1];
    float sip = hv[0] * w2[0] + hv[1] * w2[1];
#pragma unroll
    for (int o = 32; o > 0; o >>= 1) {
        sjp += __shfl_xor(sjp, o);
        sip += __shfl_xor(sip, o);
    }
    if (lane == 0) { si[row] = sip; sj[row] = sjp; }
}

// ---------------------------------------------------------------------------
// hT[b][d][j] = bf16(h[b][j][d])   (for MFMA B staging)
__global__ __launch_bounds__(256) void transpose_bf16_k(
    const float* __restrict__ h, unsigned short* __restrict__ hT)
{
    __shared__ float t[64][65];
    const int b = blockIdx.z, jt = blockIdx.x, dt = blockIdx.y;
    const int tid = threadIdx.x;
    const int r = tid >> 4, c4 = (tid & 15) * 4;
#pragma unroll
    for (int rr = 0; rr < 4; ++rr) {
        const int j = rr * 16 + r;
        f32x4 v = *(const f32x4*)(h + ((size_t)b * 1024 + jt * 64 + j) * 128 + dt * 64 + c4);
#pragma unroll
        for (int e = 0; e < 4; ++e) t[j][c4 + e] = v[e];
    }
    __syncthreads();
#pragma unroll
    for (int rr = 0; rr < 4; ++rr) {
        const int d = rr * 16 + r;
        us4 o;
#pragma unroll
        for (int e = 0; e < 4; ++e) o[e] = bf16_of(t[c4 + e][d]);
        *(us4*)(hT + ((size_t)b * 128 + dt * 64 + d) * 1024 + jt * 64 + c4) = o;
    }
}

// ---------------------------------------------------------------------------
// out[b,i,d] = sum_j sigmoid(si[i]+sj[j]+ab)*adj[b,i,j]*h[b,j,d]  (opt relu)
__global__ __launch_bounds__(256) void gnn_agg(
    const float* __restrict__ adj, const unsigned short* __restrict__ hT,
    const float* __restrict__ si, const float* __restrict__ sj,
    const float* __restrict__ abp, float* __restrict__ out, int RELU)
{
    __shared__ __align__(16) unsigned short Alds[128 * 40];  // [i][j] stride 40
    __shared__ __align__(16) unsigned short Blds[128 * 40];  // [d][j] stride 40
    const int b = blockIdx.y, it = blockIdx.x;
    const int i0 = it * 128;
    const int tid = threadIdx.x, lane = tid & 63, w = tid >> 6;
    const int quad = lane >> 4, col = lane & 15;
    const float ab = abp[0];
    const float* adjb = adj + (size_t)b * 1024 * 1024;
    const unsigned short* hTb = hT + (size_t)b * 128 * 1024;
    const float* sjb = sj + b * 1024;

    f32x4 acc[2][8] = {};
    const int sr = tid >> 1, sh = (tid & 1) * 16;
    const float sii = si[b * 1024 + i0 + sr] + ab;

    for (int j0 = 0; j0 < 1024; j0 += 32) {
        __syncthreads();
        {   // stage A: att tile 128x32 (computed on the fly)
            const float* ar = adjb + (size_t)(i0 + sr) * 1024 + j0 + sh;
            unsigned short* al = Alds + sr * 40 + sh;
#pragma unroll
            for (int q = 0; q < 16; q += 4) {
                f32x4 av = *(const f32x4*)(ar + q);
#pragma unroll
                for (int e = 0; e < 4; ++e) {
                    float s = sigm(sii + sjb[j0 + sh + q + e]) * av[e];
                    al[q + e] = bf16_of(s);
                }
            }
        }
        {   // stage B: hT rows d=0..127, 32 j's
            const unsigned short* bsrc = hTb + (size_t)sr * 1024 + j0 + sh;
            unsigned short* bl = Blds + sr * 40 + sh;
            *(short8*)&bl[0] = *(const short8*)&bsrc[0];
            *(short8*)&bl[8] = *(const short8*)&bsrc[8];
        }
        __syncthreads();
        short8 bfrag[8];
#pragma unroll
        for (int nt = 0; nt < 8; ++nt)
            bfrag[nt] = *(const short8*)&Blds[(nt * 16 + col) * 40 + quad * 8];
#pragma unroll
        for (int mt = 0; mt < 2; ++mt) {
            short8 af = *(const short8*)&Alds[((w * 2 + mt) * 16 + col) * 40 + quad * 8];
#pragma unroll
            for (int nt = 0; nt < 8; ++nt)
                acc[mt][nt] = mfma16(af, bfrag[nt], acc[mt][nt]);
        }
    }
#pragma unroll
    for (int mt = 0; mt < 2; ++mt) {
        const int ibase = i0 + (w * 2 + mt) * 16 + quad * 4;
#pragma unroll
        for (int nt = 0; nt < 8; ++nt) {
            const int d = nt * 16 + col;
#pragma unroll
            for (int r = 0; r < 4; ++r) {
                float v = acc[mt][nt][r];
                if (RELU) v = fmaxf(v, 0.f);
                out[((size_t)b * 1024 + ibase + r) * 128 + d] = v;
            }
        }
    }
}

// ---------------------------------------------------------------------------
// xw layout for the LSTM pack-domain: xw[((t*4 + pr)*8 + b)*128 + h]
//   = tmp[b*1024+t][pr*128+h] + bih + bhh,  pr in {0:i,1:f,2:g,3:o}
__global__ __launch_bounds__(256) void permute_xw(
    const float* __restrict__ tmp, const float* __restrict__ bih,
    const float* __restrict__ bhh, float* __restrict__ xw)
{
    const int idx = blockIdx.x * 256 + threadIdx.x;  // < 4194304
    const int h = idx & 127;
    const int b = (idx >> 7) & 7;
    const int pr = (idx >> 10) & 3;
    const int t = idx >> 12;
    const int r = pr * 128 + h;
    xw[idx] = tmp[((size_t)b * 1024 + t) * 512 + r] + bih[r] + bhh[r];
}

__global__ void zero_flag_k(int* f) { *f = 0; }

// ---------------------------------------------------------------------------
// Pipelined 2-layer LSTM: grid=2 blocks x 512 threads.
// Block 0 (producer) = layer 0: per-step MFMA recurrence (as round 3),
//   writes bf16 h0(t) to hbuf, publishes progress flag every 16 steps
//   (release, agent scope).
// Block 1 (consumer) = layer 1: waits per 16-step chunk (acquire), stages
//   h0 chunk into LDS via sc1 dword loads, fuses the input GEMM as 16 extra
//   MFMAs/wave (A=Wih1 regs, B=h0 LDS, separate accumulator - independent of
//   the recurrence chain), bias in regs. Writes fp32 lo1 for the heads.
// Per-step barrier = lgkmcnt(0)-only waitcnt + s_barrier builtins (keeps
// vmcnt prefetches outstanding; "memory"-clobber asm would drain vmcnt).

__device__ __forceinline__ void lstm_epilogue(
    const f32x4 accs[4], f32x4 xv0, f32x4 xv1, float* cst, float* hv, bool lo)
{
    float t0[4], t1[4];
#pragma unroll
    for (int i = 0; i < 4; ++i) {
        float P0 = 0.5f * ((lo ? accs[0][i] : dpp_shr8(accs[1][i])) + xv0[i]);
        float P1r = (lo ? accs[2][i] : dpp_shr8(accs[3][i])) + xv1[i];
        float P1 = lo ? P1r : 0.5f * P1r;
        t0[i] = tanh_f(P0);   // cols0-7: tanh(zi/2); cols8-15: tanh(zf/2)
        t1[i] = tanh_f(P1);   // cols0-7: tanh(zg);   cols8-15: tanh(zo/2)
    }
    float c2[4], og[4];
#pragma unroll
    for (int i = 0; i < 4; ++i) {
        float ig = 0.5f + 0.5f * t0[i];
        float fg = 0.5f + 0.5f * dpp_shl8(t0[i]);
        float gg = t1[i];
        og[i] = 0.5f + 0.5f * dpp_shl8(t1[i]);
        c2[i] = fg * cst[i] + ig * gg;
        cst[i] = c2[i];
    }
    float pc0 = lo ? c2[0] : dpp_shr8(c2[1]);
    float pc1 = lo ? c2[2] : dpp_shr8(c2[3]);
    float tc0 = tanh_f(pc0), tc1 = tanh_f(pc1);
    float th[4] = {tc0, dpp_shl8(tc0), tc1, dpp_shl8(tc1)};
#pragma unroll
    for (int i = 0; i < 4; ++i) hv[i] = og[i] * th[i];
}

__device__ __forceinline__ void prod_step(
    unsigned short* Hc, unsigned short* Hn, const short8 afr[4][4],
    f32x4 xv0, f32x4 xv1, float* cst, unsigned short* __restrict__ hbuf,
    int t, int col, int quad, int h4, int b)
{
    short8 bfr[4];
#pragma unroll
    for (int c = 0; c < 4; ++c)
        bfr[c] = *(const short8*)&Hc[col * 136 + c * 32 + quad * 8];
    f32x4 accs[4] = {};
#pragma unroll
    for (int c = 0; c < 4; ++c)
#pragma unroll
        for (int g = 0; g < 4; ++g)
            accs[g] = mfma16(afr[g][c], bfr[c], accs[g]);

    const bool lo = (col < 8);
    float hv[4];
    lstm_epilogue(accs, xv0, xv1, cst, hv, lo);
    if (lo) {
        us4 hb;
#pragma unroll
        for (int i = 0; i < 4; ++i) hb[i] = bf16_of(hv[i]);
        *(us4*)&Hn[b * 136 + h4] = hb;
        *(us4*)(hbuf + (size_t)t * 1024 + b * 128 + h4) = hb;
    }
    __builtin_amdgcn_s_waitcnt(0xC07F);  // lgkmcnt(0) only
    __builtin_amdgcn_s_barrier();
}

__device__ __forceinline__ void cons_step(
    unsigned short* Hc, unsigned short* Hn, const unsigned short* H0s,
    const short8 afrI[4][4], const short8 afrW[4][4],
    f32x4 bi0, f32x4 bi1, float* cst, float* __restrict__ out1,
    int t, int col, int quad, int h4, int b)
{
    // input-GEMM part: no dependence on the recurrence (H0 staged ahead)
    short8 bfr0[4];
#pragma unroll
    for (int c = 0; c < 4; ++c)
        bfr0[c] = *(const short8*)&H0s[col * 136 + c * 32 + quad * 8];
    f32x4 acc2[4] = {};
#pragma unroll
    for (int c = 0; c < 4; ++c)
#pragma unroll
        for (int g = 0; g < 4; ++g)
            acc2[g] = mfma16(afrI[g][c], bfr0[c], acc2[g]);
    // recurrent part
    short8 bfr[4];
#pragma unroll
    for (int c = 0; c < 4; ++c)
        bfr[c] = *(const short8*)&Hc[col * 136 + c * 32 + quad * 8];
    f32x4 acc[4] = {};
#pragma unroll
    for (int c = 0; c < 4; ++c)
#pragma unroll
        for (int g = 0; g < 4; ++g)
            acc[g] = mfma16(afrW[g][c], bfr[c], acc[g]);
    f32x4 accs[4];
#pragma unroll
    for (int g = 0; g < 4; ++g)
#pragma unroll
        for (int i = 0; i < 4; ++i) accs[g][i] = acc[g][i] + acc2[g][i];

    const bool lo = (col < 8);
    float hv[4];
    lstm_epilogue(accs, bi0, bi1, cst, hv, lo);
    if (lo) {
        us4 hb;
#pragma unroll
        for (int i = 0; i < 4; ++i) hb[i] = bf16_of(hv[i]);
        *(us4*)&Hn[b * 136 + h4] = hb;
        f32x4 res = {hv[0], hv[1], hv[2], hv[3]};
        *(f32x4*)(out1 + ((size_t)b * 1024 + t) * 128 + h4) = res;
    }
    __builtin_amdgcn_s_waitcnt(0xC07F);
    __builtin_amdgcn_s_barrier();
}

__global__ __launch_bounds__(512) void lstm_pipe(
    const float* __restrict__ xw0, const float* __restrict__ Whh0,
    const float* __restrict__ Wih1, const float* __restrict__ Whh1,
    const float* __restrict__ bih1, const float* __restrict__ bhh1,
    unsigned short* __restrict__ hbuf, int* __restrict__ flag,
    float* __restrict__ out1)
{
    __shared__ __align__(16) unsigned short H[2][16 * 136];
    __shared__ __align__(16) unsigned short H0[16 * 2176];  // 16 steps x [16col][136]
    const int tid = threadIdx.x;
    const int lane = tid & 63;
    const int w = tid >> 6;
    const int quad = lane >> 4;
    const int col = lane & 15;
    const int b = col & 7;
    const int prA = col >> 3;
    const int h4 = w * 16 + quad * 4;

    for (int i = tid; i < 2 * 16 * 136; i += 512) (&H[0][0])[i] = 0;
    float cst[4] = {0.f, 0.f, 0.f, 0.f};

    if (blockIdx.x == 0) {
        // ---------------- producer: layer 0 ----------------
        short8 afr[4][4];
#pragma unroll
        for (int g = 0; g < 4; ++g) {
            const int row = g * 128 + w * 16 + col;
#pragma unroll
            for (int c = 0; c < 4; ++c) {
                const float* src = Whh0 + row * 128 + c * 32 + quad * 8;
                short8 v;
#pragma unroll
                for (int j = 0; j < 8; ++j) v[j] = (short)bf16_of(src[j]);
                afr[g][c] = v;
            }
        }
        const float* xp = xw0 + (size_t)((prA * 8 + b) * 128 + h4);
        f32x4 p0a = *(const f32x4*)(xp);
        f32x4 p1a = *(const f32x4*)(xp + 2048);
        f32x4 p0b = *(const f32x4*)(xp + 4096);
        f32x4 p1b = *(const f32x4*)(xp + 6144);
        xp += 8192;
        __syncthreads();

        for (int t = 0; t < 1024; t += 2) {
            const float* xr = (t == 1022) ? xp - 8192 : xp;
            {
                f32x4 xv0 = p0a, xv1 = p1a;
                p0a = *(const f32x4*)(xr);
                p1a = *(const f32x4*)(xr + 2048);
                prod_step(&H[0][0], &H[1][0], afr, xv0, xv1, cst, hbuf, t, col, quad, h4, b);
            }
            {
                f32x4 xv0 = p0b, xv1 = p1b;
                p0b = *(const f32x4*)(xr + 4096);
                p1b = *(const f32x4*)(xr + 6144);
                prod_step(&H[1][0], &H[0][0], afr, xv0, xv1, cst, hbuf, t + 1, col, quad, h4, b);
            }
            xp += 8192;
            if ((t & 14) == 14) {   // steps 16c..16c+15 done -> publish chunk c+1
                __syncthreads();    // drain stores (vmcnt 0) across the block
                if (tid == 0)
                    __hip_atomic_store(flag, (t >> 4) + 1, __ATOMIC_RELEASE,
                                       __HIP_MEMORY_SCOPE_AGENT);
            }
        }
    } else {
        // ---------------- consumer: layer 1 ----------------
        short8 afrW[4][4], afrI[4][4];
#pragma unroll
        for (int g = 0; g < 4; ++g) {
            const int row = g * 128 + w * 16 + col;
#pragma unroll
            for (int c = 0; c < 4; ++c) {
                const float* srcW = Whh1 + row * 128 + c * 32 + quad * 8;
                const float* srcI = Wih1 + row * 128 + c * 32 + quad * 8;
                short8 vw, vi;
#pragma unroll
                for (int j = 0; j < 8; ++j) {
                    vw[j] = (short)bf16_of(srcW[j]);
                    vi[j] = (short)bf16_of(srcI[j]);
                }
                afrW[g][c] = vw;
                afrI[g][c] = vi;
            }
        }
        f32x4 bi0, bi1;
#pragma unroll
        for (int e = 0; e < 4; ++e) {
            const int r0 = prA * 128 + h4 + e;
            const int r1 = (2 + prA) * 128 + h4 + e;
            bi0[e] = bih1[r0] + bhh1[r0];
            bi1[e] = bih1[r1] + bhh1[r1];
        }
        __syncthreads();

        for (int c = 0; c < 64; ++c) {
            if (tid == 0) {
                while (__hip_atomic_load(flag, __ATOMIC_ACQUIRE,
                                         __HIP_MEMORY_SCOPE_AGENT) < c + 1)
                    __builtin_amdgcn_s_sleep(8);
            }
            __syncthreads();
            // stage chunk c: 16 steps x 8 b x 128 k bf16 = 8192 dwords
            const unsigned* src = (const unsigned*)hbuf + c * 8192;
#pragma unroll
            for (int q = 0; q < 16; ++q) {
                const int d = q * 512 + tid;
                unsigned v = __hip_atomic_load((unsigned*)(src + d), __ATOMIC_RELAXED,
                                               __HIP_MEMORY_SCOPE_AGENT);
                const int s = d >> 9, bb = (d >> 6) & 7, kh = d & 63;
                *(unsigned*)&H0[s * 2176 + bb * 136 + kh * 2] = v;
            }
            __syncthreads();
            for (int s = 0; s < 16; s += 2) {
                const int t = c * 16 + s;
                cons_step(&H[0][0], &H[1][0], &H0[s * 2176], afrI, afrW,
                          bi0, bi1, cst, out1, t, col, quad, h4, b);
                cons_step(&H[1][0], &H[0][0], &H0[(s + 1) * 2176], afrI, afrW,
                          bi0, bi1, cst, out1, t + 1, col, quad, h4, b);
            }
        }
    }
}

// ---------------------------------------------------------------------------
extern "C" void kernel_launch(void* const* d_in, const int* in_sizes, int n_in,
                              void* d_out, int out_size, void* d_ws, size_t ws_size,
                              hipStream_t stream)
{
    (void)in_sizes; (void)n_in; (void)out_size; (void)ws_size;
    const float* nf    = (const float*)d_in[0];
    const float* adj   = (const float*)d_in[1];
    const float* g1W   = (const float*)d_in[3];
    const float* g1b   = (const float*)d_in[4];
    const float* g1aW  = (const float*)d_in[5];
    const float* g1ab  = (const float*)d_in[6];
    const float* g2W   = (const float*)d_in[7];
    const float* g2b   = (const float*)d_in[8];
    const float* g2aW  = (const float*)d_in[9];
    const float* g2ab  = (const float*)d_in[10];
    const float* g3W   = (const float*)d_in[11];
    const float* g3b   = (const float*)d_in[12];
    const float* g3aW  = (const float*)d_in[13];
    const float* g3ab  = (const float*)d_in[14];
    const float* l0Wih = (const float*)d_in[15];
    const float* l0Whh = (const float*)d_in[16];
    const float* l0bih = (const float*)d_in[17];
    const float* l0bhh = (const float*)d_in[18];
    const float* l1Wih = (const float*)d_in[19];
    const float* l1Whh = (const float*)d_in[20];
    const float* l1bih = (const float*)d_in[21];
    const float* l1bhh = (const float*)d_in[22];
    const float* opW1 = (const float*)d_in[23];
    const float* opb1 = (const float*)d_in[24];
    const float* opW2 = (const float*)d_in[25];
    const float* opb2 = (const float*)d_in[26];
    const float* paW1 = (const float*)d_in[27];
    const float* pab1 = (const float*)d_in[28];
    const float* paW2 = (const float*)d_in[29];
    const float* pab2 = (const float*)d_in[30];
    const float* skW1 = (const float*)d_in[31];
    const float* skb1 = (const float*)d_in[32];
    const float* skW2 = (const float*)d_in[33];
    const float* skb2 = (const float*)d_in[34];
    const float* noW1 = (const float*)d_in[35];
    const float* nob1 = (const float*)d_in[36];
    const float* noW2 = (const float*)d_in[37];
    const float* nob2 = (const float*)d_in[38];

    float* out = (float*)d_out;
    float* ws = (float*)d_ws;
    float* bufH  = ws;                     // 1048576
    float* bufX  = ws + 1048576;           // 1048576 (gnn scratch; later hbuf)
    float* bufH3 = ws + 2097152;           // 1048576
    unsigned short* bufT = (unsigned short*)(ws + 3145728);  // 1048576 shorts
    float* siB = ws + 3670016;             // 8192
    float* sjB = ws + 3678208;             // 8192
    float* tmp = ws + 3686400;             // 4194304 (lo1 for heads)
    float* xw  = ws + 7880704;             // 4194304 (layer0 xw)
    int*   flag = (int*)(ws + 12083200);   // 1 dword
    unsigned short* hbuf = (unsigned short*)bufX;  // 2 MB, bufX dead after gnn3

    auto gemm = [&](const float* A, const float* B, const float* bias, float* C,
                    int M, int N, int K, int BT, int RELU) {
        dim3 g(N / 64, M / 64);
        gemm_f32<<<g, dim3(256), 0, stream>>>(A, B, bias, C, M, N, K, BT, RELU);
    };

    // ---- GNN layer 1 (din=64, relu)
    gemm(nf, g1W, g1b, bufH, 8192, 128, 64, 0, 0);
    sisj_kernel<<<2048, 256, 0, stream>>>(bufH, g1aW, siB, sjB);
    transpose_bf16_k<<<dim3(16, 2, 8), 256, 0, stream>>>(bufH, bufT);
    gnn_agg<<<dim3(8, 8), 256, 0, stream>>>(adj, bufT, siB, sjB, g1ab, bufX, 1);
    // ---- GNN layer 2 (relu)
    gemm(bufX, g2W, g2b, bufH, 8192, 128, 128, 0, 0);
    sisj_kernel<<<2048, 256, 0, stream>>>(bufH, g2aW, siB, sjB);
    transpose_bf16_k<<<dim3(16, 2, 8), 256, 0, stream>>>(bufH, bufT);
    gnn_agg<<<dim3(8, 8), 256, 0, stream>>>(adj, bufT, siB, sjB, g2ab, bufX, 1);
    // ---- GNN layer 3 (no relu) -> bufH3
    gemm(bufX, g3W, g3b, bufH, 8192, 128, 128, 0, 0);
    sisj_kernel<<<2048, 256, 0, stream>>>(bufH, g3aW, siB, sjB);
    transpose_bf16_k<<<dim3(16, 2, 8), 256, 0, stream>>>(bufH, bufT);
    gnn_agg<<<dim3(8, 8), 256, 0, stream>>>(adj, bufT, siB, sjB, g3ab, bufH3, 0);

    // ---- LSTM: layer0 xw precompute, then pipelined 2-layer recurrence
    gemm(bufH3, l0Wih, nullptr, tmp, 8192, 512, 128, 1, 0);
    permute_xw<<<16384, 256, 0, stream>>>(tmp, l0bih, l0bhh, xw);
    zero_flag_k<<<1, 1, 0, stream>>>(flag);
    lstm_pipe<<<2, 512, 0, stream>>>(xw, l0Whh, l1Wih, l1Whh, l1bih, l1bhh,
                                     hbuf, flag, tmp);

    // ---- heads (op, pa, sk from lo1=tmp; no from h3=bufH3)
    gemm(tmp, opW1, opb1, bufH, 8192, 128, 128, 0, 1);
    gemm(bufH, opW2, opb2, out + 0, 8192, 64, 128, 0, 0);
    gemm(tmp, paW1, pab1, bufH, 8192, 128, 128, 0, 1);
    gemm(bufH, paW2, pab2, out + 524288, 8192, 256, 128, 0, 0);
    gemm(tmp, skW1, skb1, bufH, 8192, 128, 128, 0, 1);
    gemm(bufH, skW2, skb2, out + 2621440, 8192, 128, 128, 0, 0);
    gemm(bufH3, noW1, nob1, bufH, 8192, 128, 128, 0, 1);
    gemm(bufH, noW2, nob2, out + 3670016, 8192, 64, 128, 0, 0);
}

// Round 6
// 1427.040 us; speedup vs baseline: 2.6024x; 1.3077x over previous
//
#include <hip/hip_runtime.h>

typedef __attribute__((ext_vector_type(8))) short short8;
typedef __attribute__((ext_vector_type(4))) float f32x4;
typedef __attribute__((ext_vector_type(2))) float f32x2;
typedef __attribute__((ext_vector_type(4))) unsigned short us4;
typedef __attribute__((ext_vector_type(2))) unsigned int u32x2;

__device__ __forceinline__ unsigned short bf16_of(float f) {
    unsigned u = __builtin_bit_cast(unsigned, f);
    u += 0x7fffu + ((u >> 16) & 1u);   // RNE
    return (unsigned short)(u >> 16);
}
__device__ __forceinline__ unsigned bf16pk(float a, float b) {
    return (unsigned)bf16_of(a) | ((unsigned)bf16_of(b) << 16);
}
__device__ __forceinline__ float fexp2(float x) { return __builtin_amdgcn_exp2f(x); }
__device__ __forceinline__ float frcp(float x) { return __builtin_amdgcn_rcpf(x); }
__device__ __forceinline__ float sigm(float x) { return frcp(1.f + fexp2(-1.44269504f * x)); }
__device__ __forceinline__ float tanh_f(float x) {
    float e = fexp2(2.88539008f * x);   // e^(2x)
    return 1.f - 2.f * frcp(e + 1.f);
}
__device__ __forceinline__ f32x4 mfma16(short8 a, short8 b, f32x4 c) {
    return __builtin_amdgcn_mfma_f32_16x16x32_bf16(a, b, c, 0, 0, 0);
}
// DPP cross-lane within 16-lane rows. row_shr:8 -> lane i gets lane i-8;
// row_shl:8 -> lane i gets lane i+8 (bound_ctrl: OOB reads 0).
__device__ __forceinline__ float dpp_shr8(float x) {
    return __builtin_bit_cast(float, __builtin_amdgcn_update_dpp(
        0, __builtin_bit_cast(int, x), 0x118, 0xF, 0xF, true));
}
__device__ __forceinline__ float dpp_shl8(float x) {
    return __builtin_bit_cast(float, __builtin_amdgcn_update_dpp(
        0, __builtin_bit_cast(int, x), 0x108, 0xF, 0xF, true));
}

// ---------------------------------------------------------------------------
// Generic fp32 GEMM: C[M,N] = A[M,K] @ B (+bias) (optional relu).
// BT=1: B is [N,K] row-major (use B^T). PACK=1: write in LSTM pack layout
//   (m = b*1024+t, n = pr*128+h  ->  C[((t*4+pr)*8+b)*128 + h]).
__global__ __launch_bounds__(256) void gemm_f32(
    const float* __restrict__ A, const float* __restrict__ B,
    const float* __restrict__ bias, float* __restrict__ C,
    int M, int N, int K, int BT, int RELU, int PACK)
{
    __shared__ float As[64][33];
    __shared__ float Bs[32][68];
    const int tid = threadIdx.x;
    const int tx = tid & 15, ty = tid >> 4;
    const int m0 = blockIdx.y * 64, n0 = blockIdx.x * 64;
    float acc[4][4];
#pragma unroll
    for (int i = 0; i < 4; ++i)
#pragma unroll
        for (int j = 0; j < 4; ++j) acc[i][j] = 0.f;

    for (int k0 = 0; k0 < K; k0 += 32) {
        __syncthreads();
        {   // stage A 64x32
            const int r = tid >> 2, kk = (tid & 3) * 8;
            const float* src = A + (size_t)(m0 + r) * K + k0 + kk;
            f32x4 v0 = *(const f32x4*)src;
            f32x4 v1 = *(const f32x4*)(src + 4);
#pragma unroll
            for (int e = 0; e < 4; ++e) { As[r][kk + e] = v0[e]; As[r][kk + 4 + e] = v1[e]; }
        }
        if (!BT) {  // stage B 32x64
            const int kk = tid >> 3, nn = (tid & 7) * 8;
            const float* src = B + (size_t)(k0 + kk) * N + n0 + nn;
            f32x4 v0 = *(const f32x4*)src;
            f32x4 v1 = *(const f32x4*)(src + 4);
#pragma unroll
            for (int e = 0; e < 4; ++e) { Bs[kk][nn + e] = v0[e]; Bs[kk][nn + 4 + e] = v1[e]; }
        } else {    // B given [N,K]: transpose-stage
            const int n = tid >> 2, kk = (tid & 3) * 8;
            const float* src = B + (size_t)(n0 + n) * K + k0 + kk;
            f32x4 v0 = *(const f32x4*)src;
            f32x4 v1 = *(const f32x4*)(src + 4);
#pragma unroll
            for (int e = 0; e < 4; ++e) { Bs[kk + e][n] = v0[e]; Bs[kk + 4 + e][n] = v1[e]; }
        }
        __syncthreads();
#pragma unroll 8
        for (int k = 0; k < 32; ++k) {
            float a0 = As[ty * 4 + 0][k], a1 = As[ty * 4 + 1][k];
            float a2 = As[ty * 4 + 2][k], a3 = As[ty * 4 + 3][k];
            f32x4 bv = *(const f32x4*)&Bs[k][tx * 4];
#pragma unroll
            for (int j = 0; j < 4; ++j) {
                acc[0][j] += a0 * bv[j]; acc[1][j] += a1 * bv[j];
                acc[2][j] += a2 * bv[j]; acc[3][j] += a3 * bv[j];
            }
        }
    }
    f32x4 bv = {};
    if (bias != nullptr) bv = *(const f32x4*)&bias[n0 + tx * 4];
#pragma unroll
    for (int i = 0; i < 4; ++i) {
        f32x4 res = {};
#pragma unroll
        for (int j = 0; j < 4; ++j) {
            float v = acc[i][j] + bv[j];
            if (RELU) v = fmaxf(v, 0.f);
            res[j] = v;
        }
        const int m = m0 + ty * 4 + i;
        if (!PACK) {
            *(f32x4*)&C[(size_t)m * N + n0 + tx * 4] = res;
        } else {
            const int b = m >> 10, t = m & 1023;
            const int n = n0 + tx * 4;
            const int pr = n >> 7, h = n & 127;
            *(f32x4*)&C[(((size_t)t * 4 + pr) * 8 + b) * 128 + h] = res;
        }
    }
}

// ---------------------------------------------------------------------------
// si[b,n] = h[b,n,:]·aW[128:256],  sj[b,n] = h[b,n,:]·aW[0:128]
__global__ __launch_bounds__(256) void sisj_kernel(
    const float* __restrict__ h, const float* __restrict__ aW,
    float* __restrict__ si, float* __restrict__ sj)
{
    const int tid = threadIdx.x, lane = tid & 63, w = tid >> 6;
    const int row = blockIdx.x * 4 + w;  // 0..8191
    f32x2 hv = *(const f32x2*)(h + (size_t)row * 128 + lane * 2);
    f32x2 w1 = *(const f32x2*)&aW[lane * 2];
    f32x2 w2 = *(const f32x2*)&aW[128 + lane * 2];
    float sjp = hv[0] * w1[0] + hv[1] * w1[1];
    float sip = hv[0] * w2[0] + hv[1] * w2[1];
#pragma unroll
    for (int o = 32; o > 0; o >>= 1) {
        sjp += __shfl_xor(sjp, o);
        sip += __shfl_xor(sip, o);
    }
    if (lane == 0) { si[row] = sip; sj[row] = sjp; }
}

// ---------------------------------------------------------------------------
// hT[b][d][j] = bf16(h[b][j][d])   (for MFMA B staging)
__global__ __launch_bounds__(256) void transpose_bf16_k(
    const float* __restrict__ h, unsigned short* __restrict__ hT)
{
    __shared__ float t[64][65];
    const int b = blockIdx.z, jt = blockIdx.x, dt = blockIdx.y;
    const int tid = threadIdx.x;
    const int r = tid >> 4, c4 = (tid & 15) * 4;
#pragma unroll
    for (int rr = 0; rr < 4; ++rr) {
        const int j = rr * 16 + r;
        f32x4 v = *(const f32x4*)(h + ((size_t)b * 1024 + jt * 64 + j) * 128 + dt * 64 + c4);
#pragma unroll
        for (int e = 0; e < 4; ++e) t[j][c4 + e] = v[e];
    }
    __syncthreads();
#pragma unroll
    for (int rr = 0; rr < 4; ++rr) {
        const int d = rr * 16 + r;
        u32x2 o;
        o[0] = bf16pk(t[c4 + 0][d], t[c4 + 1][d]);
        o[1] = bf16pk(t[c4 + 2][d], t[c4 + 3][d]);
        *(u32x2*)(hT + ((size_t)b * 128 + dt * 64 + d) * 1024 + jt * 64 + c4) = o;
    }
}

// ---------------------------------------------------------------------------
// out[b,i,d] = sum_j sigmoid(si[i]+sj[j]+ab)*adj[b,i,j]*h[b,j,d]  (opt relu)
// grid (16 i-tiles of 64, 8 b), 256 threads (4 waves).
__global__ __launch_bounds__(256) void gnn_agg(
    const float* __restrict__ adj, const unsigned short* __restrict__ hT,
    const float* __restrict__ si, const float* __restrict__ sj,
    const float* __restrict__ abp, float* __restrict__ out, int RELU)
{
    __shared__ __align__(16) unsigned short Alds[64 * 40];   // [i][j] stride 40
    __shared__ __align__(16) unsigned short Blds[128 * 40];  // [d][j] stride 40
    const int b = blockIdx.y, it = blockIdx.x;
    const int i0 = it * 64;
    const int tid = threadIdx.x, lane = tid & 63, w = tid >> 6;
    const int quad = lane >> 4, col = lane & 15;
    const float ab = abp[0];
    const float* adjb = adj + (size_t)b * 1024 * 1024;
    const unsigned short* hTb = hT + (size_t)b * 128 * 1024;
    const float* sjb = sj + b * 1024;

    f32x4 acc[8] = {};
    const int ar_ = tid >> 2, ash = (tid & 3) * 8;       // A-stage: 64 rows x 4thr
    const int br_ = tid >> 1, bsh = (tid & 1) * 16;      // B-stage: 128 rows x 2thr
    const float sii = si[b * 1024 + i0 + ar_] + ab;

    for (int j0 = 0; j0 < 1024; j0 += 32) {
        __syncthreads();
        {   // stage A: att tile 64x32 (computed on the fly)
            const float* ar = adjb + (size_t)(i0 + ar_) * 1024 + j0 + ash;
            f32x4 av0 = *(const f32x4*)ar;
            f32x4 av1 = *(const f32x4*)(ar + 4);
            float s[8];
#pragma unroll
            for (int e = 0; e < 4; ++e) {
                s[e]     = sigm(sii + sjb[j0 + ash + e])     * av0[e];
                s[4 + e] = sigm(sii + sjb[j0 + ash + 4 + e]) * av1[e];
            }
            u32x2 o0 = {bf16pk(s[0], s[1]), bf16pk(s[2], s[3])};
            u32x2 o1 = {bf16pk(s[4], s[5]), bf16pk(s[6], s[7])};
            unsigned short* al = Alds + ar_ * 40 + ash;
            *(u32x2*)&al[0] = o0;
            *(u32x2*)&al[4] = o1;
        }
        {   // stage B: hT rows d=0..127, 32 j's
            const unsigned short* bsrc = hTb + (size_t)br_ * 1024 + j0 + bsh;
            unsigned short* bl = Blds + br_ * 40 + bsh;
            *(short8*)&bl[0] = *(const short8*)&bsrc[0];
            *(short8*)&bl[8] = *(const short8*)&bsrc[8];
        }
        __syncthreads();
        short8 af = *(const short8*)&Alds[(w * 16 + col) * 40 + quad * 8];
#pragma unroll
        for (int nt = 0; nt < 8; ++nt) {
            short8 bf = *(const short8*)&Blds[(nt * 16 + col) * 40 + quad * 8];
            acc[nt] = mfma16(af, bf, acc[nt]);
        }
    }
    const int ibase = i0 + w * 16 + quad * 4;
#pragma unroll
    for (int nt = 0; nt < 8; ++nt) {
        const int d = nt * 16 + col;
#pragma unroll
        for (int r = 0; r < 4; ++r) {
            float v = acc[nt][r];
            if (RELU) v = fmaxf(v, 0.f);
            out[((size_t)b * 1024 + ibase + r) * 128 + d] = v;
        }
    }
}

// ---------------------------------------------------------------------------
__global__ void bsum_k(const float* a, const float* b, float* o) {
    const int i = threadIdx.x;  // 512
    o[i] = a[i] + b[i];
}
__global__ void zero_flags_k(int* f) { f[0] = 0; f[1] = 0; f[2] = 0; }

// ---------------------------------------------------------------------------
// 3-block pipelined 2-layer LSTM (1024 steps).
//  block 0 producer : layer-0 recurrence; bf16 h0 -> hbuf; flag0 += 1/16 steps
//  block 1 helper   : xw1(chunk) = h0 @ Wih1^T + bias -> 4-slot ring; flag1
//  block 2 consumer : layer-1 recurrence off ring (identical step to producer)
// flags: [0]=producer chunks, [1]=helper chunks, [2]=consumer chunks.
// Per-step barrier = lgkmcnt(0)-only waitcnt + s_barrier builtins (vmcnt
// prefetches stay outstanding; "memory"-clobber asm would drain vmcnt).

__device__ __forceinline__ void lstm_epilogue(
    const f32x4 accs[4], f32x4 xv0, f32x4 xv1, float* cst, float* hv, bool lo)
{
    float t0[4], t1[4];
#pragma unroll
    for (int i = 0; i < 4; ++i) {
        float P0 = 0.5f * ((lo ? accs[0][i] : dpp_shr8(accs[1][i])) + xv0[i]);
        float P1r = (lo ? accs[2][i] : dpp_shr8(accs[3][i])) + xv1[i];
        float P1 = lo ? P1r : 0.5f * P1r;
        t0[i] = tanh_f(P0);   // cols0-7: tanh(zi/2); cols8-15: tanh(zf/2)
        t1[i] = tanh_f(P1);   // cols0-7: tanh(zg);   cols8-15: tanh(zo/2)
    }
    float c2[4], og[4];
#pragma unroll
    for (int i = 0; i < 4; ++i) {
        float ig = 0.5f + 0.5f * t0[i];
        float fg = 0.5f + 0.5f * dpp_shl8(t0[i]);
        float gg = t1[i];
        og[i] = 0.5f + 0.5f * dpp_shl8(t1[i]);
        c2[i] = fg * cst[i] + ig * gg;
        cst[i] = c2[i];
    }
    float pc0 = lo ? c2[0] : dpp_shr8(c2[1]);
    float pc1 = lo ? c2[2] : dpp_shr8(c2[3]);
    float tc0 = tanh_f(pc0), tc1 = tanh_f(pc1);
    float th[4] = {tc0, dpp_shl8(tc0), tc1, dpp_shl8(tc1)};
#pragma unroll
    for (int i = 0; i < 4; ++i) hv[i] = og[i] * th[i];
}

// OUT32=0: sink = bf16 hbuf [t][b*128+h]; OUT32=1: sink = fp32 out [b][t][h]
template <int OUT32>
__device__ __forceinline__ void lstm_step(
    unsigned short* Hc, unsigned short* Hn, const short8 afr[4][4],
    f32x4 xv0, f32x4 xv1, float* cst, void* __restrict__ sink,
    int t, int col, int quad, int h4, int b)
{
    short8 bfr[4];
#pragma unroll
    for (int c = 0; c < 4; ++c)
        bfr[c] = *(const short8*)&Hc[col * 136 + c * 32 + quad * 8];
    f32x4 accs[4] = {};
#pragma unroll
    for (int c = 0; c < 4; ++c)
#pragma unroll
        for (int g = 0; g < 4; ++g)
            accs[g] = mfma16(afr[g][c], bfr[c], accs[g]);

    const bool lo = (col < 8);
    float hv[4];
    lstm_epilogue(accs, xv0, xv1, cst, hv, lo);
    if (lo) {
        u32x2 hb = {bf16pk(hv[0], hv[1]), bf16pk(hv[2], hv[3])};
        *(u32x2*)&Hn[b * 136 + h4] = hb;
        if (OUT32) {
            f32x4 res = {hv[0], hv[1], hv[2], hv[3]};
            *(f32x4*)((float*)sink + ((size_t)b * 1024 + t) * 128 + h4) = res;
        } else {
            *(u32x2*)((unsigned short*)sink + (size_t)t * 1024 + b * 128 + h4) = hb;
        }
    }
    __builtin_amdgcn_s_waitcnt(0xC07F);  // lgkmcnt(0) only
    __builtin_amdgcn_s_barrier();
}

__global__ __launch_bounds__(512) void lstm_pipe(
    const float* __restrict__ xw0, const float* __restrict__ Whh0,
    const float* __restrict__ Wih1, const float* __restrict__ Whh1,
    const float* __restrict__ bih1, const float* __restrict__ bhh1,
    unsigned short* __restrict__ hbuf, float* __restrict__ xw1,
    int* __restrict__ flags, float* __restrict__ out1)
{
    __shared__ __align__(16) unsigned short H[2][16 * 136];
    const int tid = threadIdx.x;
    const int lane = tid & 63;
    const int w = tid >> 6;
    const int quad = lane >> 4;
    const int col = lane & 15;
    const int b = col & 7;
    const int prA = col >> 3;
    const int h4 = w * 16 + quad * 4;

    if (blockIdx.x == 1) {
        // ---------------- helper: xw1 = h0 @ Wih1^T + bias ----------------
        short8 afrI[4][4];
        f32x4 biasv[4];
#pragma unroll
        for (int g = 0; g < 4; ++g) {
            const int row = g * 128 + w * 16 + col;
#pragma unroll
            for (int c = 0; c < 4; ++c) {
                const float* src = Wih1 + row * 128 + c * 32 + quad * 8;
                short8 v;
#pragma unroll
                for (int j = 0; j < 8; ++j) v[j] = (short)bf16_of(src[j]);
                afrI[g][c] = v;
            }
            const int rb = g * 128 + w * 16 + quad * 4;
            f32x4 b1 = *(const f32x4*)&bih1[rb];
            f32x4 b2 = *(const f32x4*)&bhh1[rb];
#pragma unroll
            for (int e = 0; e < 4; ++e) biasv[g][e] = b1[e] + b2[e];
        }
        for (int k = 0; k < 64; ++k) {
            while (__hip_atomic_load(&flags[0], __ATOMIC_ACQUIRE,
                                     __HIP_MEMORY_SCOPE_AGENT) < k + 1)
                __builtin_amdgcn_s_sleep(2);
            if (k >= 4) {
                while (__hip_atomic_load(&flags[2], __ATOMIC_RELAXED,
                                         __HIP_MEMORY_SCOPE_AGENT) < k - 3)
                    __builtin_amdgcn_s_sleep(2);
            }
            const unsigned short* hb = hbuf + (size_t)k * 16 * 1024;
            float* dst = xw1 + (size_t)(k & 3) * 65536;
#pragma unroll 2
            for (int nt = 0; nt < 8; ++nt) {
                const int tl = nt * 2 + (col >> 3);
                const unsigned short* src = hb + tl * 1024 + b * 128 + quad * 8;
                short8 bfr[4];
#pragma unroll
                for (int c = 0; c < 4; ++c) bfr[c] = *(const short8*)&src[c * 32];
                f32x4 acc[4] = {};
#pragma unroll
                for (int c = 0; c < 4; ++c)
#pragma unroll
                    for (int g = 0; g < 4; ++g)
                        acc[g] = mfma16(afrI[g][c], bfr[c], acc[g]);
#pragma unroll
                for (int g = 0; g < 4; ++g) {
                    f32x4 res;
#pragma unroll
                    for (int e = 0; e < 4; ++e) res[e] = acc[g][e] + biasv[g][e];
                    *(f32x4*)&dst[((tl * 4 + g) * 8 + b) * 128 + w * 16 + quad * 4] = res;
                }
            }
            __builtin_amdgcn_s_waitcnt(0x0F70);  // vmcnt(0) only
            __builtin_amdgcn_s_barrier();
            if (tid == 0)
                __hip_atomic_store(&flags[1], k + 1, __ATOMIC_RELEASE,
                                   __HIP_MEMORY_SCOPE_AGENT);
        }
        return;
    }

    for (int i = tid; i < 2 * 16 * 136; i += 512) (&H[0][0])[i] = 0;
    float cst[4] = {0.f, 0.f, 0.f, 0.f};
    const int lane_off = (prA * 8 + b) * 128 + h4;

    if (blockIdx.x == 0) {
        // ---------------- producer: layer 0 ----------------
        short8 afr[4][4];
#pragma unroll
        for (int g = 0; g < 4; ++g) {
            const int row = g * 128 + w * 16 + col;
#pragma unroll
            for (int c = 0; c < 4; ++c) {
                const float* src = Whh0 + row * 128 + c * 32 + quad * 8;
                short8 v;
#pragma unroll
                for (int j = 0; j < 8; ++j) v[j] = (short)bf16_of(src[j]);
                afr[g][c] = v;
            }
        }
        const float* xp = xw0 + lane_off;
        f32x4 p0a = *(const f32x4*)(xp);
        f32x4 p1a = *(const f32x4*)(xp + 2048);
        f32x4 p0b = *(const f32x4*)(xp + 4096);
        f32x4 p1b = *(const f32x4*)(xp + 6144);
        xp += 8192;
        __syncthreads();

        for (int t = 0; t < 1024; t += 2) {
            const float* xr = (t == 1022) ? xp - 8192 : xp;
            {
                f32x4 xv0 = p0a, xv1 = p1a;
                p0a = *(const f32x4*)(xr);
                p1a = *(const f32x4*)(xr + 2048);
                lstm_step<0>(&H[0][0], &H[1][0], afr, xv0, xv1, cst, hbuf, t, col, quad, h4, b);
            }
            {
                f32x4 xv0 = p0b, xv1 = p1b;
                p0b = *(const f32x4*)(xr + 4096);
                p1b = *(const f32x4*)(xr + 6144);
                lstm_step<0>(&H[1][0], &H[0][0], afr, xv0, xv1, cst, hbuf, t + 1, col, quad, h4, b);
            }
            xp += 8192;
            if ((t & 14) == 14) {   // chunk (t>>4) complete
                __syncthreads();    // drain hbuf stores across the block
                if (tid == 0)
                    __hip_atomic_store(&flags[0], (t >> 4) + 1, __ATOMIC_RELEASE,
                                       __HIP_MEMORY_SCOPE_AGENT);
            }
        }
    } else {
        // ---------------- consumer: layer 1 ----------------
        short8 afr[4][4];
#pragma unroll
        for (int g = 0; g < 4; ++g) {
            const int row = g * 128 + w * 16 + col;
#pragma unroll
            for (int c = 0; c < 4; ++c) {
                const float* src = Whh1 + row * 128 + c * 32 + quad * 8;
                short8 v;
#pragma unroll
                for (int j = 0; j < 8; ++j) v[j] = (short)bf16_of(src[j]);
                afr[g][c] = v;
            }
        }
        __syncthreads();
        // ring address for step t (slot (t/16)&3, local slot layout = xw0's)
        auto xaddr = [&](int t) -> const float* {
            return xw1 + (((t >> 4) & 3) * 65536 + (t & 15) * 4096) + lane_off;
        };
        while (__hip_atomic_load(&flags[1], __ATOMIC_ACQUIRE,
                                 __HIP_MEMORY_SCOPE_AGENT) < 2)
            __builtin_amdgcn_s_sleep(2);
        f32x4 p0a = *(const f32x4*)xaddr(0);
        f32x4 p1a = *(const f32x4*)(xaddr(0) + 2048);
        f32x4 p0b = *(const f32x4*)xaddr(1);
        f32x4 p1b = *(const f32x4*)(xaddr(1) + 2048);

        for (int c = 0; c < 64; ++c) {
            if (c > 0) {
                const int target = (c + 2 < 64) ? c + 2 : 64;
                while (__hip_atomic_load(&flags[1], __ATOMIC_ACQUIRE,
                                         __HIP_MEMORY_SCOPE_AGENT) < target)
                    __builtin_amdgcn_s_sleep(2);
            }
            for (int s = 0; s < 16; s += 2) {
                const int t = c * 16 + s;
                const int t2 = (t + 2 < 1024) ? t + 2 : 1023;
                const int t3 = (t + 3 < 1024) ? t + 3 : 1023;
                {
                    f32x4 xv0 = p0a, xv1 = p1a;
                    p0a = *(const f32x4*)xaddr(t2);
                    p1a = *(const f32x4*)(xaddr(t2) + 2048);
                    lstm_step<1>(&H[0][0], &H[1][0], afr, xv0, xv1, cst, out1, t, col, quad, h4, b);
                }
                {
                    f32x4 xv0 = p0b, xv1 = p1b;
                    p0b = *(const f32x4*)xaddr(t3);
                    p1b = *(const f32x4*)(xaddr(t3) + 2048);
                    lstm_step<1>(&H[1][0], &H[0][0], afr, xv0, xv1, cst, out1, t + 1, col, quad, h4, b);
                }
            }
            if (tid == 0)
                __hip_atomic_store(&flags[2], c + 1, __ATOMIC_RELAXED,
                                   __HIP_MEMORY_SCOPE_AGENT);
        }
    }
}

// ---------------------------------------------------------------------------
extern "C" void kernel_launch(void* const* d_in, const int* in_sizes, int n_in,
                              void* d_out, int out_size, void* d_ws, size_t ws_size,
                              hipStream_t stream)
{
    (void)in_sizes; (void)n_in; (void)out_size; (void)ws_size;
    const float* nf    = (const float*)d_in[0];
    const float* adj   = (const float*)d_in[1];
    const float* g1W   = (const float*)d_in[3];
    const float* g1b   = (const float*)d_in[4];
    const float* g1aW  = (const float*)d_in[5];
    const float* g1ab  = (const float*)d_in[6];
    const float* g2W   = (const float*)d_in[7];
    const float* g2b   = (const float*)d_in[8];
    const float* g2aW  = (const float*)d_in[9];
    const float* g2ab  = (const float*)d_in[10];
    const float* g3W   = (const float*)d_in[11];
    const float* g3b   = (const float*)d_in[12];
    const float* g3aW  = (const float*)d_in[13];
    const float* g3ab  = (const float*)d_in[14];
    const float* l0Wih = (const float*)d_in[15];
    const float* l0Whh = (const float*)d_in[16];
    const float* l0bih = (const float*)d_in[17];
    const float* l0bhh = (const float*)d_in[18];
    const float* l1Wih = (const float*)d_in[19];
    const float* l1Whh = (const float*)d_in[20];
    const float* l1bih = (const float*)d_in[21];
    const float* l1bhh = (const float*)d_in[22];
    const float* opW1 = (const float*)d_in[23];
    const float* opb1 = (const float*)d_in[24];
    const float* opW2 = (const float*)d_in[25];
    const float* opb2 = (const float*)d_in[26];
    const float* paW1 = (const float*)d_in[27];
    const float* pab1 = (const float*)d_in[28];
    const float* paW2 = (const float*)d_in[29];
    const float* pab2 = (const float*)d_in[30];
    const float* skW1 = (const float*)d_in[31];
    const float* skb1 = (const float*)d_in[32];
    const float* skW2 = (const float*)d_in[33];
    const float* skb2 = (const float*)d_in[34];
    const float* noW1 = (const float*)d_in[35];
    const float* nob1 = (const float*)d_in[36];
    const float* noW2 = (const float*)d_in[37];
    const float* nob2 = (const float*)d_in[38];

    float* out = (float*)d_out;
    float* ws = (float*)d_ws;
    float* bufH  = ws;                       // [0, 1048576)
    float* bufX  = ws + 1048576;             // [1048576, 2097152) gnn / hbuf
    float* bufH3 = ws + 2097152;             // [2097152, 3145728)
    unsigned short* bufT = (unsigned short*)(ws + 3145728);  // -> 3670016
    float* siB  = ws + 3670016;              // 8192
    float* sjB  = ws + 3678208;              // 8192
    float* bsum = ws + 3686400;              // 512
    float* out1 = ws + 3687424;              // 1048576 -> 4736000
    float* xw0  = ws + 4736000;              // 4194304 -> 8930304
    float* xw1  = ws + 8930304;              // 262144  -> 9192448 (4-slot ring)
    int*  flags = (int*)(ws + 9192448);      // 3 ints
    unsigned short* hbuf = (unsigned short*)bufX;  // 2 MB, bufX dead after gnn3

    auto gemm = [&](const float* A, const float* B, const float* bias, float* C,
                    int M, int N, int K, int BT, int RELU, int PACK = 0) {
        dim3 g(N / 64, M / 64);
        gemm_f32<<<g, dim3(256), 0, stream>>>(A, B, bias, C, M, N, K, BT, RELU, PACK);
    };

    // ---- GNN layer 1 (din=64, relu)
    gemm(nf, g1W, g1b, bufH, 8192, 128, 64, 0, 0);
    sisj_kernel<<<2048, 256, 0, stream>>>(bufH, g1aW, siB, sjB);
    transpose_bf16_k<<<dim3(16, 2, 8), 256, 0, stream>>>(bufH, bufT);
    gnn_agg<<<dim3(16, 8), 256, 0, stream>>>(adj, bufT, siB, sjB, g1ab, bufX, 1);
    // ---- GNN layer 2 (relu)
    gemm(bufX, g2W, g2b, bufH, 8192, 128, 128, 0, 0);
    sisj_kernel<<<2048, 256, 0, stream>>>(bufH, g2aW, siB, sjB);
    transpose_bf16_k<<<dim3(16, 2, 8), 256, 0, stream>>>(bufH, bufT);
    gnn_agg<<<dim3(16, 8), 256, 0, stream>>>(adj, bufT, siB, sjB, g2ab, bufX, 1);
    // ---- GNN layer 3 (no relu) -> bufH3
    gemm(bufX, g3W, g3b, bufH, 8192, 128, 128, 0, 0);
    sisj_kernel<<<2048, 256, 0, stream>>>(bufH, g3aW, siB, sjB);
    transpose_bf16_k<<<dim3(16, 2, 8), 256, 0, stream>>>(bufH, bufT);
    gnn_agg<<<dim3(16, 8), 256, 0, stream>>>(adj, bufT, siB, sjB, g3ab, bufH3, 0);

    // ---- LSTM: layer-0 xw in pack layout (bias folded), then 3-block pipe
    bsum_k<<<1, 512, 0, stream>>>(l0bih, l0bhh, bsum);
    gemm(bufH3, l0Wih, bsum, xw0, 8192, 512, 128, 1, 0, 1);
    zero_flags_k<<<1, 1, 0, stream>>>(flags);
    lstm_pipe<<<3, 512, 0, stream>>>(xw0, l0Whh, l1Wih, l1Whh, l1bih, l1bhh,
                                     hbuf, xw1, flags, out1);

    // ---- heads (op, pa, sk from lo1=out1; no from h3=bufH3)
    gemm(out1, opW1, opb1, bufH, 8192, 128, 128, 0, 1);
    gemm(bufH, opW2, opb2, out + 0, 8192, 64, 128, 0, 0);
    gemm(out1, paW1, pab1, bufH, 8192, 128, 128, 0, 1);
    gemm(bufH, paW2, pab2, out + 524288, 8192, 256, 128, 0, 0);
    gemm(out1, skW1, skb1, bufH, 8192, 128, 128, 0, 1);
    gemm(bufH, skW2, skb2, out + 2621440, 8192, 128, 128, 0, 0);
    gemm(bufH3, noW1, nob1, bufH, 8192, 128, 128, 0, 1);
    gemm(bufH, noW2, nob2, out + 3670016, 8192, 64, 128, 0, 0);
}

// Round 7
// 1400.988 us; speedup vs baseline: 2.6508x; 1.0186x over previous
//
#include <hip/hip_runtime.h>

typedef __attribute__((ext_vector_type(8))) short short8;
typedef __attribute__((ext_vector_type(4))) float f32x4;
typedef __attribute__((ext_vector_type(2))) float f32x2;
typedef __attribute__((ext_vector_type(4))) unsigned short us4;
typedef __attribute__((ext_vector_type(2))) unsigned int u32x2;

__device__ __forceinline__ unsigned short bf16_of(float f) {
    unsigned u = __builtin_bit_cast(unsigned, f);
    u += 0x7fffu + ((u >> 16) & 1u);   // RNE
    return (unsigned short)(u >> 16);
}
__device__ __forceinline__ unsigned bf16pk(float a, float b) {
    return (unsigned)bf16_of(a) | ((unsigned)bf16_of(b) << 16);
}
__device__ __forceinline__ float fexp2(float x) { return __builtin_amdgcn_exp2f(x); }
__device__ __forceinline__ float frcp(float x) { return __builtin_amdgcn_rcpf(x); }
__device__ __forceinline__ float sigm(float x) { return frcp(1.f + fexp2(-1.44269504f * x)); }
__device__ __forceinline__ float tanh_f(float x) {
    float e = fexp2(2.88539008f * x);   // e^(2x)
    return 1.f - 2.f * frcp(e + 1.f);
}
__device__ __forceinline__ f32x4 mfma16(short8 a, short8 b, f32x4 c) {
    return __builtin_amdgcn_mfma_f32_16x16x32_bf16(a, b, c, 0, 0, 0);
}
// DPP cross-lane within 16-lane rows. row_shr:8 -> lane i gets lane i-8;
// row_shl:8 -> lane i gets lane i+8 (bound_ctrl: OOB reads 0).
__device__ __forceinline__ float dpp_shr8(float x) {
    return __builtin_bit_cast(float, __builtin_amdgcn_update_dpp(
        0, __builtin_bit_cast(int, x), 0x118, 0xF, 0xF, true));
}
__device__ __forceinline__ float dpp_shl8(float x) {
    return __builtin_bit_cast(float, __builtin_amdgcn_update_dpp(
        0, __builtin_bit_cast(int, x), 0x108, 0xF, 0xF, true));
}

// ---------------------------------------------------------------------------
// Generic fp32 GEMM: C[M,N] = A[M,K] @ B (+bias) (optional relu).
// BT=1: B is [N,K] row-major (use B^T). PACK=1: write in LSTM pack layout.
__global__ __launch_bounds__(256) void gemm_f32(
    const float* __restrict__ A, const float* __restrict__ B,
    const float* __restrict__ bias, float* __restrict__ C,
    int M, int N, int K, int BT, int RELU, int PACK)
{
    __shared__ float As[64][33];
    __shared__ float Bs[32][68];
    const int tid = threadIdx.x;
    const int tx = tid & 15, ty = tid >> 4;
    const int m0 = blockIdx.y * 64, n0 = blockIdx.x * 64;
    float acc[4][4];
#pragma unroll
    for (int i = 0; i < 4; ++i)
#pragma unroll
        for (int j = 0; j < 4; ++j) acc[i][j] = 0.f;

    for (int k0 = 0; k0 < K; k0 += 32) {
        __syncthreads();
        {   // stage A 64x32
            const int r = tid >> 2, kk = (tid & 3) * 8;
            const float* src = A + (size_t)(m0 + r) * K + k0 + kk;
            f32x4 v0 = *(const f32x4*)src;
            f32x4 v1 = *(const f32x4*)(src + 4);
#pragma unroll
            for (int e = 0; e < 4; ++e) { As[r][kk + e] = v0[e]; As[r][kk + 4 + e] = v1[e]; }
        }
        if (!BT) {  // stage B 32x64
            const int kk = tid >> 3, nn = (tid & 7) * 8;
            const float* src = B + (size_t)(k0 + kk) * N + n0 + nn;
            f32x4 v0 = *(const f32x4*)src;
            f32x4 v1 = *(const f32x4*)(src + 4);
#pragma unroll
            for (int e = 0; e < 4; ++e) { Bs[kk][nn + e] = v0[e]; Bs[kk][nn + 4 + e] = v1[e]; }
        } else {    // B given [N,K]: transpose-stage
            const int n = tid >> 2, kk = (tid & 3) * 8;
            const float* src = B + (size_t)(n0 + n) * K + k0 + kk;
            f32x4 v0 = *(const f32x4*)src;
            f32x4 v1 = *(const f32x4*)(src + 4);
#pragma unroll
            for (int e = 0; e < 4; ++e) { Bs[kk + e][n] = v0[e]; Bs[kk + 4 + e][n] = v1[e]; }
        }
        __syncthreads();
#pragma unroll 8
        for (int k = 0; k < 32; ++k) {
            float a0 = As[ty * 4 + 0][k], a1 = As[ty * 4 + 1][k];
            float a2 = As[ty * 4 + 2][k], a3 = As[ty * 4 + 3][k];
            f32x4 bv = *(const f32x4*)&Bs[k][tx * 4];
#pragma unroll
            for (int j = 0; j < 4; ++j) {
                acc[0][j] += a0 * bv[j]; acc[1][j] += a1 * bv[j];
                acc[2][j] += a2 * bv[j]; acc[3][j] += a3 * bv[j];
            }
        }
    }
    f32x4 bv = {};
    if (bias != nullptr) bv = *(const f32x4*)&bias[n0 + tx * 4];
#pragma unroll
    for (int i = 0; i < 4; ++i) {
        f32x4 res = {};
#pragma unroll
        for (int j = 0; j < 4; ++j) {
            float v = acc[i][j] + bv[j];
            if (RELU) v = fmaxf(v, 0.f);
            res[j] = v;
        }
        const int m = m0 + ty * 4 + i;
        if (!PACK) {
            *(f32x4*)&C[(size_t)m * N + n0 + tx * 4] = res;
        } else {
            const int b = m >> 10, t = m & 1023;
            const int n = n0 + tx * 4;
            const int pr = n >> 7, h = n & 127;
            *(f32x4*)&C[(((size_t)t * 4 + pr) * 8 + b) * 128 + h] = res;
        }
    }
}

// ---------------------------------------------------------------------------
__global__ __launch_bounds__(256) void sisj_kernel(
    const float* __restrict__ h, const float* __restrict__ aW,
    float* __restrict__ si, float* __restrict__ sj)
{
    const int tid = threadIdx.x, lane = tid & 63, w = tid >> 6;
    const int row = blockIdx.x * 4 + w;  // 0..8191
    f32x2 hv = *(const f32x2*)(h + (size_t)row * 128 + lane * 2);
    f32x2 w1 = *(const f32x2*)&aW[lane * 2];
    f32x2 w2 = *(const f32x2*)&aW[128 + lane * 2];
    float sjp = hv[0] * w1[0] + hv[1] * w1[1];
    float sip = hv[0] * w2[0] + hv[1] * w2[1];
#pragma unroll
    for (int o = 32; o > 0; o >>= 1) {
        sjp += __shfl_xor(sjp, o);
        sip += __shfl_xor(sip, o);
    }
    if (lane == 0) { si[row] = sip; sj[row] = sjp; }
}

// ---------------------------------------------------------------------------
// hT[b][d][j] = bf16(h[b][j][d])   (for MFMA B staging)
__global__ __launch_bounds__(256) void transpose_bf16_k(
    const float* __restrict__ h, unsigned short* __restrict__ hT)
{
    __shared__ float t[64][65];
    const int b = blockIdx.z, jt = blockIdx.x, dt = blockIdx.y;
    const int tid = threadIdx.x;
    const int r = tid >> 4, c4 = (tid & 15) * 4;
#pragma unroll
    for (int rr = 0; rr < 4; ++rr) {
        const int j = rr * 16 + r;
        f32x4 v = *(const f32x4*)(h + ((size_t)b * 1024 + jt * 64 + j) * 128 + dt * 64 + c4);
#pragma unroll
        for (int e = 0; e < 4; ++e) t[j][c4 + e] = v[e];
    }
    __syncthreads();
#pragma unroll
    for (int rr = 0; rr < 4; ++rr) {
        const int d = rr * 16 + r;
        u32x2 o;
        o[0] = bf16pk(t[c4 + 0][d], t[c4 + 1][d]);
        o[1] = bf16pk(t[c4 + 2][d], t[c4 + 3][d]);
        *(u32x2*)(hT + ((size_t)b * 128 + dt * 64 + d) * 1024 + jt * 64 + c4) = o;
    }
}

// ---------------------------------------------------------------------------
// out[b,i,d] = sum_j sigmoid(si[i]+sj[j]+ab)*adj[b,i,j]*h[b,j,d]  (opt relu)
__global__ __launch_bounds__(256) void gnn_agg(
    const float* __restrict__ adj, const unsigned short* __restrict__ hT,
    const float* __restrict__ si, const float* __restrict__ sj,
    const float* __restrict__ abp, float* __restrict__ out, int RELU)
{
    __shared__ __align__(16) unsigned short Alds[64 * 40];   // [i][j] stride 40
    __shared__ __align__(16) unsigned short Blds[128 * 40];  // [d][j] stride 40
    const int b = blockIdx.y, it = blockIdx.x;
    const int i0 = it * 64;
    const int tid = threadIdx.x, lane = tid & 63, w = tid >> 6;
    const int quad = lane >> 4, col = lane & 15;
    const float ab = abp[0];
    const float* adjb = adj + (size_t)b * 1024 * 1024;
    const unsigned short* hTb = hT + (size_t)b * 128 * 1024;
    const float* sjb = sj + b * 1024;

    f32x4 acc[8] = {};
    const int ar_ = tid >> 2, ash = (tid & 3) * 8;       // A-stage: 64 rows x 4thr
    const int br_ = tid >> 1, bsh = (tid & 1) * 16;      // B-stage: 128 rows x 2thr
    const float sii = si[b * 1024 + i0 + ar_] + ab;

    for (int j0 = 0; j0 < 1024; j0 += 32) {
        __syncthreads();
        {   // stage A: att tile 64x32 (computed on the fly)
            const float* ar = adjb + (size_t)(i0 + ar_) * 1024 + j0 + ash;
            f32x4 av0 = *(const f32x4*)ar;
            f32x4 av1 = *(const f32x4*)(ar + 4);
            float s[8];
#pragma unroll
            for (int e = 0; e < 4; ++e) {
                s[e]     = sigm(sii + sjb[j0 + ash + e])     * av0[e];
                s[4 + e] = sigm(sii + sjb[j0 + ash + 4 + e]) * av1[e];
            }
            u32x2 o0 = {bf16pk(s[0], s[1]), bf16pk(s[2], s[3])};
            u32x2 o1 = {bf16pk(s[4], s[5]), bf16pk(s[6], s[7])};
            unsigned short* al = Alds + ar_ * 40 + ash;
            *(u32x2*)&al[0] = o0;
            *(u32x2*)&al[4] = o1;
        }
        {   // stage B: hT rows d=0..127, 32 j's
            const unsigned short* bsrc = hTb + (size_t)br_ * 1024 + j0 + bsh;
            unsigned short* bl = Blds + br_ * 40 + bsh;
            *(short8*)&bl[0] = *(const short8*)&bsrc[0];
            *(short8*)&bl[8] = *(const short8*)&bsrc[8];
        }
        __syncthreads();
        short8 af = *(const short8*)&Alds[(w * 16 + col) * 40 + quad * 8];
#pragma unroll
        for (int nt = 0; nt < 8; ++nt) {
            short8 bf = *(const short8*)&Blds[(nt * 16 + col) * 40 + quad * 8];
            acc[nt] = mfma16(af, bf, acc[nt]);
        }
    }
    const int ibase = i0 + w * 16 + quad * 4;
#pragma unroll
    for (int nt = 0; nt < 8; ++nt) {
        const int d = nt * 16 + col;
#pragma unroll
        for (int r = 0; r < 4; ++r) {
            float v = acc[nt][r];
            if (RELU) v = fmaxf(v, 0.f);
            out[((size_t)b * 1024 + ibase + r) * 128 + d] = v;
        }
    }
}

// ---------------------------------------------------------------------------
// Prep: transpose+bf16 the 8 head weight matrices to [n][k] layout, plus
// bsum = l0bih+l0bhh and flag zeroing. One launch, 9 blocks.
struct PrepArgs {
    const float* src[8];
    unsigned short* dst[8];
    int N[8];
};
__global__ __launch_bounds__(256) void prep_k(
    PrepArgs pa, const float* bih0, const float* bhh0,
    float* bsum, int* flags)
{
    const int m = blockIdx.x;
    const int tid = threadIdx.x;
    if (m < 8) {
        const float* src = pa.src[m];
        unsigned short* dst = pa.dst[m];
        const int N = pa.N[m];
        const int n0 = tid >> 4, kc = (tid & 15) * 8;
        for (int n = n0; n < N; n += 16) {
            unsigned o[4];
#pragma unroll
            for (int e = 0; e < 8; e += 2)
                o[e >> 1] = bf16pk(src[(size_t)(kc + e) * N + n],
                                   src[(size_t)(kc + e + 1) * N + n]);
            *(u32x2*)&dst[n * 128 + kc] = *(u32x2*)&o[0];
            *(u32x2*)&dst[n * 128 + kc + 4] = *(u32x2*)&o[2];
        }
    } else {
        bsum[tid] = bih0[tid] + bhh0[tid];
        bsum[tid + 256] = bih0[tid + 256] + bhh0[tid + 256];
        if (tid < 3) flags[tid] = 0;
    }
}

// ---------------------------------------------------------------------------
// 11-block lstm_pipe: 2-layer LSTM pipeline + fused MLP heads.
//  block 0 producer : layer-0 recurrence -> bf16 hbuf; flags[0] += 1/16 steps
//  block 1 helper   : xw1(chunk) = h0 @ Wih1^T + bias -> 4-slot ring; flags[1]
//  block 2 consumer : layer-1 recurrence off ring -> bf16 out1b; flags[2]
//  blocks 3-10      : head workers: `no` head (bufH3) immediately; op/pa/sk
//                     per 128-row strip as flags[2] publishes chunks.
// Per-step barrier = lgkmcnt(0)-only waitcnt + s_barrier builtins (vmcnt
// prefetches stay outstanding). Flag waits are tid0-guarded: wave-0's
// acquire (buffer_inv) covers the CU's L1; other waves just barrier.

struct HeadArgs {
    const unsigned short* W1T[4];
    const float* b1[4];
    const unsigned short* W2T[4];
    const float* b2[4];
    float* outp[4];       // op, pa, sk, no
};

__device__ __forceinline__ void lstm_epilogue(
    const f32x4 accs[4], f32x4 xv0, f32x4 xv1, float* cst, float* hv, bool lo)
{
    float t0[4], t1[4];
#pragma unroll
    for (int i = 0; i < 4; ++i) {
        float P0 = 0.5f * ((lo ? accs[0][i] : dpp_shr8(accs[1][i])) + xv0[i]);
        float P1r = (lo ? accs[2][i] : dpp_shr8(accs[3][i])) + xv1[i];
        float P1 = lo ? P1r : 0.5f * P1r;
        t0[i] = tanh_f(P0);   // cols0-7: tanh(zi/2); cols8-15: tanh(zf/2)
        t1[i] = tanh_f(P1);   // cols0-7: tanh(zg);   cols8-15: tanh(zo/2)
    }
    float c2[4], og[4];
#pragma unroll
    for (int i = 0; i < 4; ++i) {
        float ig = 0.5f + 0.5f * t0[i];
        float fg = 0.5f + 0.5f * dpp_shl8(t0[i]);
        float gg = t1[i];
        og[i] = 0.5f + 0.5f * dpp_shl8(t1[i]);
        c2[i] = fg * cst[i] + ig * gg;
        cst[i] = c2[i];
    }
    float pc0 = lo ? c2[0] : dpp_shr8(c2[1]);
    float pc1 = lo ? c2[2] : dpp_shr8(c2[3]);
    float tc0 = tanh_f(pc0), tc1 = tanh_f(pc1);
    float th[4] = {tc0, dpp_shl8(tc0), tc1, dpp_shl8(tc1)};
#pragma unroll
    for (int i = 0; i < 4; ++i) hv[i] = og[i] * th[i];
}

// SINK=0: bf16 hbuf [t*1024 + b*128 + h]; SINK=1: bf16 out1b [(t*8+b)*128 + h]
template <int SINK>
__device__ __forceinline__ void lstm_step(
    unsigned short* Hc, unsigned short* Hn, const short8 afr[4][4],
    f32x4 xv0, f32x4 xv1, float* cst, unsigned short* __restrict__ sink,
    int t, int col, int quad, int h4, int b)
{
    short8 bfr[4];
#pragma unroll
    for (int c = 0; c < 4; ++c)
        bfr[c] = *(const short8*)&Hc[col * 136 + c * 32 + quad * 8];
    f32x4 accs[4] = {};
#pragma unroll
    for (int c = 0; c < 4; ++c)
#pragma unroll
        for (int g = 0; g < 4; ++g)
            accs[g] = mfma16(afr[g][c], bfr[c], accs[g]);

    const bool lo = (col < 8);
    float hv[4];
    lstm_epilogue(accs, xv0, xv1, cst, hv, lo);
    if (lo) {
        u32x2 hb = {bf16pk(hv[0], hv[1]), bf16pk(hv[2], hv[3])};
        *(u32x2*)&Hn[b * 136 + h4] = hb;
        if (SINK == 0)
            *(u32x2*)(sink + (size_t)t * 1024 + b * 128 + h4) = hb;
        else
            *(u32x2*)(sink + ((size_t)t * 8 + b) * 128 + h4) = hb;
    }
    __builtin_amdgcn_s_waitcnt(0xC07F);  // lgkmcnt(0) only
    __builtin_amdgcn_s_barrier();
}

// One 128-row strip of a 2-layer MLP head (8 waves / 512 threads).
// A32=1: Asrc fp32 [row][128]; else bf16 [row][128].
// LROWS=1: global row r encodes (t=r>>3, b=r&7) -> out[(b*1024+t)*dout + n];
// else out[r*dout + n].
template <int A32, int LROWS>
__device__ void head_strip(
    const void* __restrict__ Asrc, int row0,
    const unsigned short* __restrict__ W1T, const float* __restrict__ b1,
    const unsigned short* __restrict__ W2T, const float* __restrict__ b2,
    float* __restrict__ outp, int dout, unsigned short* A2, int tid)
{
    const int lane = tid & 63, w = tid >> 6;
    const int quad = lane >> 4, col = lane & 15;
    const int mrow = w * 16 + col;          // A-frag row within strip
    // GEMM1: [128 x 128] @ W1T -> relu -> A2 (bf16)
    f32x4 acc[8] = {};
#pragma unroll
    for (int kc = 0; kc < 4; ++kc) {
        short8 af;
        if (A32) {
            const float* s = (const float*)Asrc + (size_t)(row0 + mrow) * 128 + kc * 32 + quad * 8;
            f32x4 v0 = *(const f32x4*)s, v1 = *(const f32x4*)(s + 4);
            short8 v;
#pragma unroll
            for (int j = 0; j < 4; ++j) {
                v[j] = (short)bf16_of(v0[j]);
                v[4 + j] = (short)bf16_of(v1[j]);
            }
            af = v;
        } else {
            af = *(const short8*)((const unsigned short*)Asrc +
                                  (size_t)(row0 + mrow) * 128 + kc * 32 + quad * 8);
        }
#pragma unroll
        for (int nt = 0; nt < 8; ++nt) {
            short8 bf = *(const short8*)&W1T[(nt * 16 + col) * 128 + kc * 32 + quad * 8];
            acc[nt] = mfma16(af, bf, acc[nt]);
        }
    }
    float b1v[8];
#pragma unroll
    for (int nt = 0; nt < 8; ++nt) b1v[nt] = b1[nt * 16 + col];
    __syncthreads();   // previous strip's A2 reads done
#pragma unroll
    for (int nt = 0; nt < 8; ++nt)
#pragma unroll
        for (int i = 0; i < 4; ++i) {
            const int mm = w * 16 + quad * 4 + i;
            A2[mm * 136 + nt * 16 + col] = bf16_of(fmaxf(acc[nt][i] + b1v[nt], 0.f));
        }
    __syncthreads();
    // GEMM2: A2 @ W2T -> out (+b2)
    const int ntiles = dout >> 4;
    for (int np = 0; np < ntiles; np += 8) {
        const int nts = (ntiles - np < 8) ? ntiles - np : 8;
        f32x4 acc2[8] = {};
#pragma unroll
        for (int kc = 0; kc < 4; ++kc) {
            short8 a2f = *(const short8*)&A2[mrow * 136 + kc * 32 + quad * 8];
            for (int nt = 0; nt < nts; ++nt) {
                short8 bf = *(const short8*)&W2T[((np + nt) * 16 + col) * 128 + kc * 32 + quad * 8];
                acc2[nt] = mfma16(a2f, bf, acc2[nt]);
            }
        }
        for (int nt = 0; nt < nts; ++nt) {
            const int n = (np + nt) * 16 + col;
            const float bb = b2[n];
#pragma unroll
            for (int i = 0; i < 4; ++i) {
                const int r = row0 + w * 16 + quad * 4 + i;
                size_t off;
                if (LROWS) off = ((size_t)(r & 7) * 1024 + (r >> 3)) * dout + n;
                else       off = (size_t)r * dout + n;
                outp[off] = acc2[nt][i] + bb;
            }
        }
    }
}

__global__ __launch_bounds__(512) void lstm_pipe(
    const float* __restrict__ xw0, const float* __restrict__ Whh0,
    const float* __restrict__ Wih1, const float* __restrict__ Whh1,
    const float* __restrict__ bih1, const float* __restrict__ bhh1,
    unsigned short* __restrict__ hbuf, float* __restrict__ xw1,
    int* __restrict__ flags, unsigned short* __restrict__ out1b,
    const float* __restrict__ bufH3, HeadArgs ha)
{
    __shared__ __align__(16) unsigned short H[2][16 * 136];
    __shared__ __align__(16) unsigned short A2[128 * 136];
    const int tid = threadIdx.x;
    const int lane = tid & 63;
    const int w = tid >> 6;
    const int quad = lane >> 4;
    const int col = lane & 15;
    const int b = col & 7;
    const int prA = col >> 3;
    const int h4 = w * 16 + quad * 4;

    if (blockIdx.x >= 3) {
        // ---------------- head workers ----------------
        const int wid = blockIdx.x - 3;   // 0..7
        for (int s = wid; s < 64; s += 8)
            head_strip<1, 0>(bufH3, s * 128, ha.W1T[3], ha.b1[3],
                             ha.W2T[3], ha.b2[3], ha.outp[3], 64, A2, tid);
        for (int s = wid; s < 64; s += 8) {
            if (tid == 0) {
                while (__hip_atomic_load(&flags[2], __ATOMIC_ACQUIRE,
                                         __HIP_MEMORY_SCOPE_AGENT) < s + 1)
                    __builtin_amdgcn_s_sleep(16);
            }
            __syncthreads();
            head_strip<0, 1>(out1b, s * 128, ha.W1T[0], ha.b1[0],
                             ha.W2T[0], ha.b2[0], ha.outp[0], 64, A2, tid);
            head_strip<0, 1>(out1b, s * 128, ha.W1T[1], ha.b1[1],
                             ha.W2T[1], ha.b2[1], ha.outp[1], 256, A2, tid);
            head_strip<0, 1>(out1b, s * 128, ha.W1T[2], ha.b1[2],
                             ha.W2T[2], ha.b2[2], ha.outp[2], 128, A2, tid);
        }
        return;
    }

    if (blockIdx.x == 1) {
        // ---------------- helper: xw1 = h0 @ Wih1^T + bias ----------------
        short8 afrI[4][4];
        f32x4 biasv[4];
#pragma unroll
        for (int g = 0; g < 4; ++g) {
            const int row = g * 128 + w * 16 + col;
#pragma unroll
            for (int c = 0; c < 4; ++c) {
                const float* src = Wih1 + row * 128 + c * 32 + quad * 8;
                short8 v;
#pragma unroll
                for (int j = 0; j < 8; ++j) v[j] = (short)bf16_of(src[j]);
                afrI[g][c] = v;
            }
            const int rb = g * 128 + w * 16 + quad * 4;
            f32x4 b1 = *(const f32x4*)&bih1[rb];
            f32x4 b2 = *(const f32x4*)&bhh1[rb];
#pragma unroll
            for (int e = 0; e < 4; ++e) biasv[g][e] = b1[e] + b2[e];
        }
        for (int k = 0; k < 64; ++k) {
            if (tid == 0) {
                while (__hip_atomic_load(&flags[0], __ATOMIC_ACQUIRE,
                                         __HIP_MEMORY_SCOPE_AGENT) < k + 1)
                    __builtin_amdgcn_s_sleep(2);
                if (k >= 4) {
                    while (__hip_atomic_load(&flags[2], __ATOMIC_RELAXED,
                                             __HIP_MEMORY_SCOPE_AGENT) < k - 3)
                        __builtin_amdgcn_s_sleep(2);
                }
            }
            __builtin_amdgcn_s_waitcnt(0xC07F);
            __builtin_amdgcn_s_barrier();
            const unsigned short* hb = hbuf + (size_t)k * 16 * 1024;
            float* dst = xw1 + (size_t)(k & 3) * 65536;
#pragma unroll 2
            for (int nt = 0; nt < 8; ++nt) {
                const int tl = nt * 2 + (col >> 3);
                const unsigned short* src = hb + tl * 1024 + b * 128 + quad * 8;
                short8 bfr[4];
#pragma unroll
                for (int c = 0; c < 4; ++c) bfr[c] = *(const short8*)&src[c * 32];
                f32x4 acc[4] = {};
#pragma unroll
                for (int c = 0; c < 4; ++c)
#pragma unroll
                    for (int g = 0; g < 4; ++g)
                        acc[g] = mfma16(afrI[g][c], bfr[c], acc[g]);
#pragma unroll
                for (int g = 0; g < 4; ++g) {
                    f32x4 res;
#pragma unroll
                    for (int e = 0; e < 4; ++e) res[e] = acc[g][e] + biasv[g][e];
                    *(f32x4*)&dst[((tl * 4 + g) * 8 + b) * 128 + w * 16 + quad * 4] = res;
                }
            }
            __builtin_amdgcn_s_waitcnt(0x0F70);  // vmcnt(0) only
            __builtin_amdgcn_s_barrier();
            if (tid == 0)
                __hip_atomic_store(&flags[1], k + 1, __ATOMIC_RELEASE,
                                   __HIP_MEMORY_SCOPE_AGENT);
        }
        return;
    }

    for (int i = tid; i < 2 * 16 * 136; i += 512) (&H[0][0])[i] = 0;
    float cst[4] = {0.f, 0.f, 0.f, 0.f};
    const int lane_off = (prA * 8 + b) * 128 + h4;

    if (blockIdx.x == 0) {
        // ---------------- producer: layer 0 ----------------
        short8 afr[4][4];
#pragma unroll
        for (int g = 0; g < 4; ++g) {
            const int row = g * 128 + w * 16 + col;
#pragma unroll
            for (int c = 0; c < 4; ++c) {
                const float* src = Whh0 + row * 128 + c * 32 + quad * 8;
                short8 v;
#pragma unroll
                for (int j = 0; j < 8; ++j) v[j] = (short)bf16_of(src[j]);
                afr[g][c] = v;
            }
        }
        const float* xp = xw0 + lane_off;
        f32x4 p0a = *(const f32x4*)(xp);
        f32x4 p1a = *(const f32x4*)(xp + 2048);
        f32x4 p0b = *(const f32x4*)(xp + 4096);
        f32x4 p1b = *(const f32x4*)(xp + 6144);
        xp += 8192;
        __syncthreads();

        for (int t = 0; t < 1024; t += 2) {
            const float* xr = (t == 1022) ? xp - 8192 : xp;
            {
                f32x4 xv0 = p0a, xv1 = p1a;
                p0a = *(const f32x4*)(xr);
                p1a = *(const f32x4*)(xr + 2048);
                lstm_step<0>(&H[0][0], &H[1][0], afr, xv0, xv1, cst, hbuf, t, col, quad, h4, b);
            }
            {
                f32x4 xv0 = p0b, xv1 = p1b;
                p0b = *(const f32x4*)(xr + 4096);
                p1b = *(const f32x4*)(xr + 6144);
                lstm_step<0>(&H[1][0], &H[0][0], afr, xv0, xv1, cst, hbuf, t + 1, col, quad, h4, b);
            }
            xp += 8192;
            if ((t & 14) == 14) {   // chunk (t>>4) complete
                __syncthreads();    // drain hbuf stores across the block
                if (tid == 0)
                    __hip_atomic_store(&flags[0], (t >> 4) + 1, __ATOMIC_RELEASE,
                                       __HIP_MEMORY_SCOPE_AGENT);
            }
        }
    } else {
        // ---------------- consumer: layer 1 ----------------
        short8 afr[4][4];
#pragma unroll
        for (int g = 0; g < 4; ++g) {
            const int row = g * 128 + w * 16 + col;
#pragma unroll
            for (int c = 0; c < 4; ++c) {
                const float* src = Whh1 + row * 128 + c * 32 + quad * 8;
                short8 v;
#pragma unroll
                for (int j = 0; j < 8; ++j) v[j] = (short)bf16_of(src[j]);
                afr[g][c] = v;
            }
        }
        __syncthreads();
        auto xaddr = [&](int t) -> const float* {
            return xw1 + (((t >> 4) & 3) * 65536 + (t & 15) * 4096) + lane_off;
        };
        while (__hip_atomic_load(&flags[1], __ATOMIC_ACQUIRE,
                                 __HIP_MEMORY_SCOPE_AGENT) < 2)
            __builtin_amdgcn_s_sleep(2);
        f32x4 p0a = *(const f32x4*)xaddr(0);
        f32x4 p1a = *(const f32x4*)(xaddr(0) + 2048);
        f32x4 p0b = *(const f32x4*)xaddr(1);
        f32x4 p1b = *(const f32x4*)(xaddr(1) + 2048);

        for (int c = 0; c < 64; ++c) {
            if (c > 0) {
                const int target = (c + 2 < 64) ? c + 2 : 64;
                if (tid == 0) {
                    while (__hip_atomic_load(&flags[1], __ATOMIC_ACQUIRE,
                                             __HIP_MEMORY_SCOPE_AGENT) < target)
                        __builtin_amdgcn_s_sleep(2);
                }
                __builtin_amdgcn_s_waitcnt(0xC07F);
                __builtin_amdgcn_s_barrier();
            }
            for (int s = 0; s < 16; s += 2) {
                const int t = c * 16 + s;
                const int t2 = (t + 2 < 1024) ? t + 2 : 1023;
                const int t3 = (t + 3 < 1024) ? t + 3 : 1023;
                {
                    f32x4 xv0 = p0a, xv1 = p1a;
                    p0a = *(const f32x4*)xaddr(t2);
                    p1a = *(const f32x4*)(xaddr(t2) + 2048);
                    lstm_step<1>(&H[0][0], &H[1][0], afr, xv0, xv1, cst, out1b, t, col, quad, h4, b);
                }
                {
                    f32x4 xv0 = p0b, xv1 = p1b;
                    p0b = *(const f32x4*)xaddr(t3);
                    p1b = *(const f32x4*)(xaddr(t3) + 2048);
                    lstm_step<1>(&H[1][0], &H[0][0], afr, xv0, xv1, cst, out1b, t + 1, col, quad, h4, b);
                }
            }
            __syncthreads();   // drain out1b stores before publishing chunk
            if (tid == 0)
                __hip_atomic_store(&flags[2], c + 1, __ATOMIC_RELEASE,
                                   __HIP_MEMORY_SCOPE_AGENT);
        }
    }
}

// ---------------------------------------------------------------------------
extern "C" void kernel_launch(void* const* d_in, const int* in_sizes, int n_in,
                              void* d_out, int out_size, void* d_ws, size_t ws_size,
                              hipStream_t stream)
{
    (void)in_sizes; (void)n_in; (void)out_size; (void)ws_size;
    const float* nf    = (const float*)d_in[0];
    const float* adj   = (const float*)d_in[1];
    const float* g1W   = (const float*)d_in[3];
    const float* g1b   = (const float*)d_in[4];
    const float* g1aW  = (const float*)d_in[5];
    const float* g1ab  = (const float*)d_in[6];
    const float* g2W   = (const float*)d_in[7];
    const float* g2b   = (const float*)d_in[8];
    const float* g2aW  = (const float*)d_in[9];
    const float* g2ab  = (const float*)d_in[10];
    const float* g3W   = (const float*)d_in[11];
    const float* g3b   = (const float*)d_in[12];
    const float* g3aW  = (const float*)d_in[13];
    const float* g3ab  = (const float*)d_in[14];
    const float* l0Wih = (const float*)d_in[15];
    const float* l0Whh = (const float*)d_in[16];
    const float* l0bih = (const float*)d_in[17];
    const float* l0bhh = (const float*)d_in[18];
    const float* l1Wih = (const float*)d_in[19];
    const float* l1Whh = (const float*)d_in[20];
    const float* l1bih = (const float*)d_in[21];
    const float* l1bhh = (const float*)d_in[22];
    const float* opW1 = (const float*)d_in[23];
    const float* opb1 = (const float*)d_in[24];
    const float* opW2 = (const float*)d_in[25];
    const float* opb2 = (const float*)d_in[26];
    const float* paW1 = (const float*)d_in[27];
    const float* pab1 = (const float*)d_in[28];
    const float* paW2 = (const float*)d_in[29];
    const float* pab2 = (const float*)d_in[30];
    const float* skW1 = (const float*)d_in[31];
    const float* skb1 = (const float*)d_in[32];
    const float* skW2 = (const float*)d_in[33];
    const float* skb2 = (const float*)d_in[34];
    const float* noW1 = (const float*)d_in[35];
    const float* nob1 = (const float*)d_in[36];
    const float* noW2 = (const float*)d_in[37];
    const float* nob2 = (const float*)d_in[38];

    float* out = (float*)d_out;
    float* ws = (float*)d_ws;
    float* bufH  = ws;                       // [0, 1048576)
    float* bufX  = ws + 1048576;             // gnn ping / later hbuf
    float* bufH3 = ws + 2097152;             // gnn3 out (node head input)
    unsigned short* bufT = (unsigned short*)(ws + 3145728);  // -> 3670016
    float* siB  = ws + 3670016;              // 8192
    float* sjB  = ws + 3678208;              // 8192
    float* bsum = ws + 3686400;              // 512
    float* xw0  = ws + 3687424;              // 4194304 -> 7881728
    float* xw1  = ws + 7881728;              // 262144  -> 8143872 (4-slot ring)
    int*  flags = (int*)(ws + 8143872);      // 3 ints
    unsigned short* WT = (unsigned short*)(ws + 8143876);    // 131072 shorts
    unsigned short* out1b = (unsigned short*)(ws + 8209412); // 1048576 shorts
    unsigned short* hbuf = (unsigned short*)bufX;            // 2 MB

    unsigned short* opW1T = WT;
    unsigned short* paW1T = WT + 16384;
    unsigned short* skW1T = WT + 32768;
    unsigned short* noW1T = WT + 49152;
    unsigned short* opW2T = WT + 65536;
    unsigned short* paW2T = WT + 73728;
    unsigned short* skW2T = WT + 106496;
    unsigned short* noW2T = WT + 122880;

    auto gemm = [&](const float* A, const float* B, const float* bias, float* C,
                    int M, int N, int K, int BT, int RELU, int PACK = 0) {
        dim3 g(N / 64, M / 64);
        gemm_f32<<<g, dim3(256), 0, stream>>>(A, B, bias, C, M, N, K, BT, RELU, PACK);
    };

    // ---- GNN layer 1 (din=64, relu)
    gemm(nf, g1W, g1b, bufH, 8192, 128, 64, 0, 0);
    sisj_kernel<<<2048, 256, 0, stream>>>(bufH, g1aW, siB, sjB);
    transpose_bf16_k<<<dim3(16, 2, 8), 256, 0, stream>>>(bufH, bufT);
    gnn_agg<<<dim3(16, 8), 256, 0, stream>>>(adj, bufT, siB, sjB, g1ab, bufX, 1);
    // ---- GNN layer 2 (relu)
    gemm(bufX, g2W, g2b, bufH, 8192, 128, 128, 0, 0);
    sisj_kernel<<<2048, 256, 0, stream>>>(bufH, g2aW, siB, sjB);
    transpose_bf16_k<<<dim3(16, 2, 8), 256, 0, stream>>>(bufH, bufT);
    gnn_agg<<<dim3(16, 8), 256, 0, stream>>>(adj, bufT, siB, sjB, g2ab, bufX, 1);
    // ---- GNN layer 3 (no relu) -> bufH3
    gemm(bufX, g3W, g3b, bufH, 8192, 128, 128, 0, 0);
    sisj_kernel<<<2048, 256, 0, stream>>>(bufH, g3aW, siB, sjB);
    transpose_bf16_k<<<dim3(16, 2, 8), 256, 0, stream>>>(bufH, bufT);
    gnn_agg<<<dim3(16, 8), 256, 0, stream>>>(adj, bufT, siB, sjB, g3ab, bufH3, 0);

    // ---- prep (head weight transposes + bsum + flag zero)
    PrepArgs pargs;
    pargs.src[0] = opW1; pargs.dst[0] = opW1T; pargs.N[0] = 128;
    pargs.src[1] = paW1; pargs.dst[1] = paW1T; pargs.N[1] = 128;
    pargs.src[2] = skW1; pargs.dst[2] = skW1T; pargs.N[2] = 128;
    pargs.src[3] = noW1; pargs.dst[3] = noW1T; pargs.N[3] = 128;
    pargs.src[4] = opW2; pargs.dst[4] = opW2T; pargs.N[4] = 64;
    pargs.src[5] = paW2; pargs.dst[5] = paW2T; pargs.N[5] = 256;
    pargs.src[6] = skW2; pargs.dst[6] = skW2T; pargs.N[6] = 128;
    pargs.src[7] = noW2; pargs.dst[7] = noW2T; pargs.N[7] = 64;
    prep_k<<<9, 256, 0, stream>>>(pargs, l0bih, l0bhh, bsum, flags);

    // ---- layer-0 xw in pack layout (bias folded)
    gemm(bufH3, l0Wih, bsum, xw0, 8192, 512, 128, 1, 0, 1);

    // ---- pipelined LSTM + fused heads
    HeadArgs ha;
    ha.W1T[0] = opW1T; ha.b1[0] = opb1; ha.W2T[0] = opW2T; ha.b2[0] = opb2;
    ha.outp[0] = out + 0;
    ha.W1T[1] = paW1T; ha.b1[1] = pab1; ha.W2T[1] = paW2T; ha.b2[1] = pab2;
    ha.outp[1] = out + 524288;
    ha.W1T[2] = skW1T; ha.b1[2] = skb1; ha.W2T[2] = skW2T; ha.b2[2] = skb2;
    ha.outp[2] = out + 2621440;
    ha.W1T[3] = noW1T; ha.b1[3] = nob1; ha.W2T[3] = noW2T; ha.b2[3] = nob2;
    ha.outp[3] = out + 3670016;
    lstm_pipe<<<11, 512, 0, stream>>>(xw0, l0Whh, l1Wih, l1Whh, l1bih, l1bhh,
                                      hbuf, xw1, flags, out1b, bufH3, ha);
}